// Round 1
// baseline (540.128 us; speedup 1.0000x reference)
//
#include <hip/hip_runtime.h>
#include <hip/hip_bf16.h>
#include <math.h>

#define Bz 2
#define Sz 2048
#define Dz 1024
#define Hz 16
#define HDz 64
#define Fz 4096
#define ROWS (Bz*Sz)          // 4096
#define EPSf 1e-5f
#define NEGf -1e9f

typedef __attribute__((ext_vector_type(8))) short short8;   // 8 bf16 (4 VGPRs)
typedef __attribute__((ext_vector_type(4))) float floatx4;  // MFMA C/D

__device__ __forceinline__ unsigned short f2bf(float f){
  __hip_bfloat16 h = __float2bfloat16(f);
  return *(unsigned short*)&h;
}
__device__ __forceinline__ float bf2f(unsigned short u){
  union { unsigned x; float f; } a; a.x = ((unsigned)u) << 16; return a.f;
}

// exact-accuracy gelu via A&S 7.1.26 erf (|err|<=1.5e-7)
__device__ __forceinline__ float fast_gelu(float x){
  float t  = fabsf(x) * 0.70710678118654752f;
  float kk = __builtin_amdgcn_rcpf(1.0f + 0.3275911f * t);
  float poly = ((((1.061405429f*kk - 1.453152027f)*kk + 1.421413741f)*kk
                 - 0.284496736f)*kk + 0.254829592f)*kk;
  float er = 1.0f - poly * __expf(-t*t);
  er = copysignf(er, x);
  return 0.5f * x * (1.0f + er);
}

// async global->LDS, 16 B per lane, LDS dest = wave-uniform base + lane*16
__device__ __forceinline__ void gload16(const void* g, void* l){
  __builtin_amdgcn_global_load_lds(
      (const __attribute__((address_space(1))) unsigned int*)g,
      (__attribute__((address_space(3))) unsigned int*)l, 16, 0, 0);
}

// raw barrier (no implicit vmcnt(0) drain, unlike __syncthreads)
__device__ __forceinline__ void bar(){
  asm volatile("" ::: "memory");
  __builtin_amdgcn_s_barrier();
  asm volatile("" ::: "memory");
}
#define WAITV6 asm volatile("s_waitcnt vmcnt(6)" ::: "memory")
#define WAITV0 asm volatile("s_waitcnt vmcnt(0)" ::: "memory")
#define WL0    asm volatile("s_waitcnt lgkmcnt(0)" ::: "memory")

// XCD-clustered block remap (used by gemm_n64)
__device__ __forceinline__ void xcd_remap(int& bmblk, int& bnblk){
  int gx = gridDim.x, gy = gridDim.y;
  int id = blockIdx.y * gx + blockIdx.x;
  int xcd = id & 7, local = id >> 3;
  bnblk = local % gx;
  bmblk = xcd * (gy >> 3) + local / gx;
}

// ---------------- weight transpose + fp32->bf16 cast: W[K][N] -> Wt[N][K] ---
__global__ __launch_bounds__(256)
void transpose_cast(const float* __restrict__ W, unsigned short* __restrict__ Wt,
                    int K, int N)
{
  __shared__ unsigned short Ts[32][33];
  int n0 = blockIdx.x*32, k0 = blockIdx.y*32;
  int r = threadIdx.x >> 3, c0 = (threadIdx.x & 7) * 4;
  float4 w4 = *(const float4*)(W + (size_t)(k0+r)*N + n0 + c0);
  Ts[r][c0+0] = f2bf(w4.x); Ts[r][c0+1] = f2bf(w4.y);
  Ts[r][c0+2] = f2bf(w4.z); Ts[r][c0+3] = f2bf(w4.w);
  __syncthreads();
  unsigned v0 = Ts[c0+0][r], v1 = Ts[c0+1][r], v2 = Ts[c0+2][r], v3 = Ts[c0+3][r];
  uint2 p; p.x = v0 | (v1<<16); p.y = v2 | (v3<<16);
  *(uint2*)(Wt + (size_t)(n0+r)*K + k0 + c0) = p;
}

// ---------------- LayerNorm: fp32 in -> bf16 out, one block per row --------
__global__ __launch_bounds__(256)
void ln_kernel(const float* __restrict__ in, const float* __restrict__ gam,
               const float* __restrict__ bet, unsigned short* __restrict__ out)
{
  int row = blockIdx.x, t = threadIdx.x;
  size_t base = (size_t)row * Dz;
  int c0 = t * 4;
  float4 x4 = *(const float4*)(in + base + c0);
  float v[4] = {x4.x, x4.y, x4.z, x4.w};
  float s = v[0]+v[1]+v[2]+v[3];
  #pragma unroll
  for (int off=32; off>0; off>>=1) s += __shfl_down(s, off, 64);
  __shared__ float ws[4];
  int lane = t & 63, wid = t >> 6;
  if (lane == 0) ws[wid] = s;
  __syncthreads();
  float mu = (ws[0]+ws[1]+ws[2]+ws[3]) * (1.0f/Dz);
  __syncthreads();
  float d0=v[0]-mu, d1=v[1]-mu, d2=v[2]-mu, d3=v[3]-mu;
  float s2 = d0*d0+d1*d1+d2*d2+d3*d3;
  #pragma unroll
  for (int off=32; off>0; off>>=1) s2 += __shfl_down(s2, off, 64);
  if (lane == 0) ws[wid] = s2;
  __syncthreads();
  float var = (ws[0]+ws[1]+ws[2]+ws[3]) * (1.0f/Dz);
  float rstd = rsqrtf(var + EPSf);
  float4 g4 = *(const float4*)(gam + c0);
  float4 b4 = *(const float4*)(bet + c0);
  unsigned r0 = f2bf((v[0]-mu)*rstd*g4.x + b4.x);
  unsigned r1 = f2bf((v[1]-mu)*rstd*g4.y + b4.y);
  unsigned r2 = f2bf((v[2]-mu)*rstd*g4.z + b4.z);
  unsigned r3 = f2bf((v[3]-mu)*rstd*g4.w + b4.w);
  uint2 p; p.x = r0 | (r1<<16); p.y = r2 | (r3<<16);
  *(uint2*)(out + base + c0) = p;
}

// ===========================================================================
// 256x256-tile, BK=64, 8-wave, 8-phase GEMM (HK-style schedule, plain HIP).
// LDS 128 KiB = 2 K-tile buffers x (A 256x64 + B 256x64) bf16.
// Per phase: {ds_read frags | issue 1 region global_load_lds} -> s_barrier ->
// lgkmcnt(0) -> setprio(1) 16xMFMA setprio(0) -> s_barrier.
// Counted s_waitcnt vmcnt(6) only at phases 4 and 8 (3 regions in flight);
// never 0 in steady state.  XOR slot-swizzle on LDS reads, inverse-swizzled
// global sources for the linear global_load_lds writes (both-sides rule).
//
// Region schedule (iter t computes K-tiles 2t (buf0, ph1-4), 2t+1 (buf1, 5-8)):
//   ph1 stage buf1.B-jh1(2t+1)   [old read ph7 prev iter]
//   ph2 stage buf0.A-even(2t+2)  [read ph1]   ph3 stage buf0.A-odd  [ph2]
//   ph4 stage buf0.B-jh0 + vmcnt(6)           ph5 stage buf0.B-jh1  [ph3]
//   ph6 stage buf1.A-even(2t+3)  [ph5]        ph7 stage buf1.A-odd  [ph6]
//   ph8 stage buf1.B-jh0 + vmcnt(6)
// vmcnt(6)@ph4 proves everything through ph1's stage landed (buf1 complete);
// vmcnt(6)@ph8 proves through ph5's stage landed (buf0 next K-tile complete).
// ===========================================================================
#define STG_A(buf, half, k0) { \
  _Pragma("unroll") for (int c_=0;c_<2;c_++){ \
    int sg_ = c_*8 + wave; \
    int row0_ = ((sg_>>3)<<7) + ((sg_&7)<<3) + ((half)<<6); \
    gload16(pA[half][c_] + (k0), &As[buf][row0_*64]); } }

#define STG_B(buf, jh, k0) { \
  _Pragma("unroll") for (int c_=0;c_<2;c_++){ \
    int sg_ = c_*8 + wave; int rho0_ = sg_<<3; \
    gload16(pB[jh][c_] + (k0), &Bs[buf][jh][rho0_*64]); } }

#define READ_A4(dst, buf, ihalf) { \
  _Pragma("unroll") for (int ii_=0; ii_<4; ++ii_){ \
    int row_ = wm*128 + ((ihalf)*4+ii_)*16 + l15; \
    _Pragma("unroll") for (int ks_=0; ks_<2; ++ks_){ \
      int slot_ = (ks_*4+quad) ^ (l15&7); \
      dst[ii_][ks_] = *(const short8*)&As[buf][row_*64 + slot_*8]; } } }

#define READ_B2(dst, buf, jh) { \
  _Pragma("unroll") for (int jl_=0; jl_<2; ++jl_){ \
    int rho_ = wn*32 + jl_*16 + l15; \
    _Pragma("unroll") for (int ks_=0; ks_<2; ++ks_){ \
      int slot_ = (ks_*4+quad) ^ (l15&7); \
      dst[jl_][ks_] = *(const short8*)&Bs[buf][jh][rho_*64 + slot_*8]; } } }

#define MFMA_PH(IH, JH, AF, BF) { \
  __builtin_amdgcn_s_setprio(1); \
  _Pragma("unroll") for (int ii_=0; ii_<4; ++ii_){ \
    _Pragma("unroll") for (int jl_=0; jl_<2; ++jl_){ \
      floatx4 c_ = acc[(IH)*4+ii_][(JH)*2+jl_]; \
      c_ = __builtin_amdgcn_mfma_f32_16x16x32_bf16(AF[ii_][0], BF[jl_][0], c_, 0,0,0); \
      c_ = __builtin_amdgcn_mfma_f32_16x16x32_bf16(AF[ii_][1], BF[jl_][1], c_, 0,0,0); \
      acc[(IH)*4+ii_][(JH)*2+jl_] = c_; } } \
  __builtin_amdgcn_s_setprio(0); }

__global__ __launch_bounds__(512, 2)
void gemm256(const unsigned short* __restrict__ A,
             const unsigned short* __restrict__ Bt,
             const float* __restrict__ bias, const float* __restrict__ res,
             float* __restrict__ outf, unsigned short* __restrict__ outb,
             int M, int N, int K, int lda, int ldb, int act, int qkvmode)
{
  __shared__ unsigned short As[2][256*64];     // [buf][row(256)][k(64)], swizzled slots
  __shared__ unsigned short Bs[2][2][128*64];  // [buf][jh][wn*32+jl*16+l15][k(64)]

  int t = threadIdx.x;
  int wave = t >> 6, lane = t & 63;
  int l15 = lane & 15, quad = lane >> 4;
  int wm = wave >> 2, wn = wave & 3;           // 2x4 wave grid, wave tile 128x64

  // bijective XCD-clustered remap (requires gridDim.y % 8 == 0)
  int nN = gridDim.x, nM = gridDim.y;
  int id = blockIdx.y * nN + blockIdx.x;
  int xcd = id & 7, local = id >> 3;
  int bnblk = local % nN;
  int bmblk = xcd * (nM >> 3) + local / nN;
  int bm = bmblk * 256, bn = bnblk * 256;

  // split-K via blockIdx.z: chunk c uses A/B k-columns [c*K, (c+1)*K), writes
  // fp32 partial c (outf must be non-null, bias/res null).
  if (gridDim.z > 1){
    A    += (size_t)blockIdx.z * K;
    Bt   += (size_t)blockIdx.z * K;
    outf += (size_t)blockIdx.z * ((size_t)M * N);
  }

  int lrow = lane >> 3;                         // 0..7 rows within a 1KB piece
  int lcol = ((lane & 7) ^ (lane >> 3)) * 8;    // inverse-swizzled source chunk

  // precomputed per-lane global source pointers (k0 added per stage)
  const unsigned short* pA[2][2];
  const unsigned short* pB[2][2];
  #pragma unroll
  for (int half=0; half<2; half++)
    #pragma unroll
    for (int c=0;c<2;c++){
      int sg = c*8 + wave;
      int row0 = ((sg>>3)<<7) + ((sg&7)<<3) + (half<<6);
      pA[half][c] = A + (size_t)(bm + row0 + lrow)*lda + lcol;
    }
  #pragma unroll
  for (int jh=0; jh<2; jh++)
    #pragma unroll
    for (int c=0;c<2;c++){
      int sg = c*8 + wave;
      int rho0 = sg<<3;
      int gn = ((rho0>>5)<<6) + (jh<<5) + (rho0&31);
      pB[jh][c] = Bt + (size_t)(bn + gn + lrow)*ldb + lcol;
    }

  floatx4 acc[8][4];
  #pragma unroll
  for (int i=0;i<8;i++)
    #pragma unroll
    for (int j=0;j<4;j++) acc[i][j] = (floatx4){0.f,0.f,0.f,0.f};

  // prologue: buf0 <- K-tile 0 (all 4 regions), buf1 <- K-tile 1 (3 regions;
  // B-jh1 staged at phase 1 of iter 0, matching steady state)
  STG_A(0, 0, 0);  STG_A(0, 1, 0);
  STG_B(0, 0, 0);  STG_B(0, 1, 0);
  STG_A(1, 0, 64); STG_A(1, 1, 64);
  STG_B(1, 0, 64);
  WAITV6;                     // buf0's 8 loads landed; buf1's 6 in flight
  bar();

  int NKT = K >> 6;           // 64-wide K-tiles (even for all our shapes)
  int nIter = NKT >> 1;
  for (int it = 0; it < nIter; ++it){
    bool more = (it + 1 < nIter);
    int k0B  = (2*it+1) << 6;
    int k0A2 = (2*it+2) << 6;
    int k0B2 = (2*it+3) << 6;
    short8 aLo[4][2], aHi[4][2], bcur[2][2];

    // ---- phase 1: buf0 i0..3 x j0..1 ----
    READ_A4(aLo, 0, 0);
    READ_B2(bcur, 0, 0);
    STG_B(1, 1, k0B);
    bar(); WL0;
    MFMA_PH(0, 0, aLo, bcur);
    bar();

    // ---- phase 2: buf0 i4..7 x j0..1 ----
    READ_A4(aHi, 0, 1);
    READ_B2(bcur, 0, 0);
    if (more) STG_A(0, 0, k0A2);
    bar(); WL0;
    MFMA_PH(1, 0, aHi, bcur);
    bar();

    // ---- phase 3: buf0 i0..3 x j2..3 (aLo held) ----
    READ_B2(bcur, 0, 1);
    if (more) STG_A(0, 1, k0A2);
    bar(); WL0;
    MFMA_PH(0, 1, aLo, bcur);
    bar();

    // ---- phase 4: buf0 i4..7 x j2..3 (aHi, bcur held) ----
    if (more) { STG_B(0, 0, k0A2); WAITV6; }
    else      { WAITV0; }
    bar();
    MFMA_PH(1, 1, aHi, bcur);
    bar();

    // ---- phase 5: buf1 i0..3 x j0..1 ----
    READ_A4(aLo, 1, 0);
    READ_B2(bcur, 1, 0);
    if (more) STG_B(0, 1, k0A2);
    bar(); WL0;
    MFMA_PH(0, 0, aLo, bcur);
    bar();

    // ---- phase 6: buf1 i4..7 x j0..1 ----
    READ_A4(aHi, 1, 1);
    READ_B2(bcur, 1, 0);
    if (more) STG_A(1, 0, k0B2);
    bar(); WL0;
    MFMA_PH(1, 0, aHi, bcur);
    bar();

    // ---- phase 7: buf1 i0..3 x j2..3 ----
    READ_B2(bcur, 1, 1);
    if (more) STG_A(1, 1, k0B2);
    bar(); WL0;
    MFMA_PH(0, 1, aLo, bcur);
    bar();

    // ---- phase 8: buf1 i4..7 x j2..3 ----
    if (more) { STG_B(1, 0, k0B2); WAITV6; }
    bar();
    MFMA_PH(1, 1, aHi, bcur);
    bar();
  }

  // ---- epilogue ----
  float bj[4];
  #pragma unroll
  for (int j=0;j<4;j++) bj[j] = bias ? bias[bn + wn*64 + j*16 + l15] : 0.f;

  size_t selbase = 0; int ncol = N; int bnl = bn;
  if (qkvmode){ selbase = (size_t)(bn >> 10) * ((size_t)M * 1024); ncol = 1024; bnl = bn & 1023; }

  #pragma unroll
  for (int i=0;i<8;i++){
    int row0 = bm + wm*128 + i*16 + quad*4;
    #pragma unroll
    for (int r=0;r<4;r++){
      size_t rowoff = selbase + (size_t)(row0 + r) * ncol;
      #pragma unroll
      for (int j=0;j<4;j++){
        float v = acc[i][j][r] + bj[j];
        if (act) v = fast_gelu(v);
        size_t off = rowoff + bnl + wn*64 + j*16 + l15;
        if (res) v += res[off];
        if (outf) outf[off] = v;
        else      outb[off] = f2bf(v);
      }
    }
  }
}

// ---------------- MFMA GEMM 128x64, BK=64, double-buffered ------------------
__global__ __launch_bounds__(256)
void gemm_n64(const unsigned short* __restrict__ A,
              const unsigned short* __restrict__ Bt,
              const float* __restrict__ bias, const float* __restrict__ res,
              float* __restrict__ outf, unsigned short* __restrict__ outb,
              int M, int N, int K)
{
  __shared__ unsigned short As[2][128*64];   // [m][k], swizzled blocks
  __shared__ unsigned short Bs[2][64*64];    // [n][k]
  int t = threadIdx.x;
  int bmblk, bnblk; xcd_remap(bmblk, bnblk);
  int bm = bmblk * 128, bn = bnblk * 64;
  int wave = t >> 6, lane = t & 63;
  int l15 = lane & 15, quad = lane >> 4;
  int arow = lane >> 3;
  int acbg = ((lane & 7) ^ arow) * 8;
  const unsigned short* gA = A  + (size_t)(bm + wave*32 + arow)*K + acbg;
  const unsigned short* gB = Bt + (size_t)(bn + wave*16 + arow)*K + acbg;

  floatx4 acc[2][4];
  #pragma unroll
  for (int i=0;i<2;i++)
    #pragma unroll
    for (int j=0;j<4;j++) acc[i][j] = (floatx4){0.f,0.f,0.f,0.f};

  int swr = (l15 & 7);   // read-side XOR key

  { // prologue: tile 0 -> buffer 0
    unsigned short* lA = &As[0][wave*32*64];
    unsigned short* lB = &Bs[0][wave*16*64];
    gload16(gA,                 lA);
    gload16(gA + (size_t)8*K,   lA + 8*64);
    gload16(gA + (size_t)16*K,  lA + 16*64);
    gload16(gA + (size_t)24*K,  lA + 24*64);
    gload16(gB,                 lB);
    gload16(gB + (size_t)8*K,   lB + 8*64);
  }

  int nIter = K >> 6;
  for (int it = 0; it < nIter; ++it) {
    __syncthreads();
    int cur = it & 1;
    if (it + 1 < nIter) {
      int k1 = (it+1) << 6;
      unsigned short* lA = &As[cur^1][wave*32*64];
      unsigned short* lB = &Bs[cur^1][wave*16*64];
      gload16(gA + k1,                 lA);
      gload16(gA + k1 + (size_t)8*K,   lA + 8*64);
      gload16(gA + k1 + (size_t)16*K,  lA + 16*64);
      gload16(gA + k1 + (size_t)24*K,  lA + 24*64);
      gload16(gB + k1,                 lB);
      gload16(gB + k1 + (size_t)8*K,   lB + 8*64);
    }
    const unsigned short* Ac = As[cur];
    const unsigned short* Bc = Bs[cur];
    #pragma unroll
    for (int ks=0; ks<2; ++ks){
      short8 af[2], bf[4];
      #pragma unroll
      for (int i=0;i<2;i++)
        af[i] = *(const short8*)&Ac[(wave*32 + i*16 + l15)*64 + ((ks*4 + quad) ^ swr)*8];
      #pragma unroll
      for (int j=0;j<4;j++)
        bf[j] = *(const short8*)&Bc[(j*16 + l15)*64 + ((ks*4 + quad) ^ swr)*8];
      #pragma unroll
      for (int i=0;i<2;i++)
        #pragma unroll
        for (int j=0;j<4;j++)
          acc[i][j] = __builtin_amdgcn_mfma_f32_16x16x32_bf16(af[i], bf[j], acc[i][j], 0, 0, 0);
    }
  }

  float bj[4];
  #pragma unroll
  for (int j=0;j<4;j++) bj[j] = bias ? bias[bn + j*16 + l15] : 0.f;

  #pragma unroll
  for (int i=0;i<2;i++){
    int row0 = bm + wave*32 + i*16 + quad*4;
    #pragma unroll
    for (int r=0;r<4;r++){
      size_t rowoff = (size_t)(row0 + r) * N;
      #pragma unroll
      for (int j=0;j<4;j++){
        float v = acc[i][j][r] + bj[j];
        size_t off = rowoff + bn + j*16 + l15;
        if (res) v += res[off];
        if (outf) outf[off] = v;
        else      outb[off] = f2bf(v);
      }
    }
  }
}

// ---------------- split-K reduce: out = sum(part[0..3]) + bias + res --------
__global__ __launch_bounds__(256)
void reduce4(const float* __restrict__ part, const float* __restrict__ bias,
             const float* __restrict__ res, float* __restrict__ out)
{
  const size_t NN = (size_t)ROWS * Dz;
  size_t i = ((size_t)blockIdx.x * 256 + threadIdx.x) * 4;  // one block per row
  float4 a = *(const float4*)(part + i);
  float4 b = *(const float4*)(part + NN + i);
  float4 c = *(const float4*)(part + 2*NN + i);
  float4 d = *(const float4*)(part + 3*NN + i);
  float4 r = *(const float4*)(res + i);
  int col = threadIdx.x * 4;
  float4 g = *(const float4*)(bias + col);
  float4 o;
  o.x = a.x+b.x+c.x+d.x + g.x + r.x;
  o.y = a.y+b.y+c.y+d.y + g.y + r.y;
  o.z = a.z+b.z+c.z+d.z + g.z + r.z;
  o.w = a.w+b.w+c.w+d.w + g.w + r.w;
  *(float4*)(out + i) = o;
}

// ---------------- V column-mean per (b,h): for the all-masked row S-1 -------
__global__ __launch_bounds__(256)
void vmean_kernel(const unsigned short* __restrict__ v, float* __restrict__ vm)
{
  int h = blockIdx.x, b = blockIdx.y;
  int t = threadIdx.x, d = t & 63, seg = t >> 6;
  float s = 0.f;
  for (int i=0;i<512;i++){
    int srow = seg*512 + i;
    s += bf2f(v[((size_t)(b*Sz + srow))*Dz + h*HDz + d]);
  }
  __shared__ float red[4][64];
  red[seg][d] = s;
  __syncthreads();
  if (seg == 0){
    float tot = red[0][d]+red[1][d]+red[2][d]+red[3][d];
    vm[(b*Hz + h)*HDz + d] = tot * (1.0f/2048.0f);
  }
}

// ---------------- MFMA flash attention, register-prefetched K/V tiles -------
__global__ __launch_bounds__(256)
void attn_mfma(const unsigned short* __restrict__ Qg,
               const unsigned short* __restrict__ Kg,
               const unsigned short* __restrict__ Vg,
               const float* __restrict__ vmean,
               unsigned short* __restrict__ Og)
{
  __shared__ unsigned short Ks[128][72];
  __shared__ unsigned short Vts[64][136];  // [dim][key], 128 keys
  __shared__ unsigned short Ps[128][72];   // Q staging, then P (wave-private rows)

  int t = threadIdx.x;
  int wave = t >> 6, lane = t & 63;
  int l15 = lane & 15, quad = lane >> 4;
  int b = blockIdx.z, h = blockIdx.y;
  int qt = b ? (15 - (int)blockIdx.x) : (int)blockIdx.x;   // load-balance pairing

  { // stage Q tile (128 x 64) into Ps; wave w writes exactly rows 32w..32w+31
    int r = t >> 1, c = (t & 1) * 32;
    const unsigned short* qp = Qg + ((size_t)(b*Sz + qt*128 + r))*Dz + h*HDz + c;
    uint4 q0 = *(const uint4*)(qp);
    uint4 q1 = *(const uint4*)(qp + 8);
    uint4 q2 = *(const uint4*)(qp + 16);
    uint4 q3 = *(const uint4*)(qp + 24);
    *(uint4*)&Ps[r][c]      = q0;
    *(uint4*)&Ps[r][c + 8]  = q1;
    *(uint4*)&Ps[r][c + 16] = q2;
    *(uint4*)&Ps[r][c + 24] = q3;
  }
  __syncthreads();
  short8 aq[2][2];
  #pragma unroll
  for (int i=0;i<2;i++)
    #pragma unroll
    for (int ks=0;ks<2;ks++)
      aq[i][ks] = *(const short8*)&Ps[wave*32 + i*16 + l15][ks*32 + quad*8];

  floatx4 acc_o[2][4];
  #pragma unroll
  for (int i=0;i<2;i++)
    #pragma unroll
    for (int j=0;j<4;j++) acc_o[i][j] = (floatx4){0.f,0.f,0.f,0.f};
  float lacc[2][4];
  #pragma unroll
  for (int i=0;i<2;i++)
    #pragma unroll
    for (int r=0;r<4;r++) lacc[i][r] = 0.f;

  int sr = t >> 2, sc = (t & 3) * 16;

  uint4 pk0,pk1,pk2,pk3,pv0,pv1,pv2,pv3;
  { // preload first tile into registers
    size_t off0 = ((size_t)(b*Sz + qt*128 + sr))*Dz + h*HDz + sc;
    size_t off1 = off0 + (size_t)64*Dz;
    pk0 = *(const uint4*)(Kg + off0); pk1 = *(const uint4*)(Kg + off0 + 8);
    pk2 = *(const uint4*)(Kg + off1); pk3 = *(const uint4*)(Kg + off1 + 8);
    pv0 = *(const uint4*)(Vg + off0); pv1 = *(const uint4*)(Vg + off0 + 8);
    pv2 = *(const uint4*)(Vg + off1); pv3 = *(const uint4*)(Vg + off1 + 8);
  }

  for (int jt2 = qt; jt2 < Sz/128; ++jt2) {
    __syncthreads();
    { // stage K tile and V^T tile from prefetched registers
      *(uint4*)&Ks[sr][sc]        = pk0; *(uint4*)&Ks[sr][sc + 8]      = pk1;
      *(uint4*)&Ks[64 + sr][sc]   = pk2; *(uint4*)&Ks[64 + sr][sc + 8] = pk3;
      unsigned short e[16];
      e[0]=pv0.x&0xffff; e[1]=pv0.x>>16; e[2]=pv0.y&0xffff; e[3]=pv0.y>>16;
      e[4]=pv0.z&0xffff; e[5]=pv0.z>>16; e[6]=pv0.w&0xffff; e[7]=pv0.w>>16;
      e[8]=pv1.x&0xffff; e[9]=pv1.x>>16; e[10]=pv1.y&0xffff; e[11]=pv1.y>>16;
      e[12]=pv1.z&0xffff; e[13]=pv1.z>>16; e[14]=pv1.w&0xffff; e[15]=pv1.w>>16;
      #pragma unroll
      for (int j=0;j<16;j++) Vts[sc + j][sr] = e[j];
      e[0]=pv2.x&0xffff; e[1]=pv2.x>>16; e[2]=pv2.y&0xffff; e[3]=pv2.y>>16;
      e[4]=pv2.z&0xffff; e[5]=pv2.z>>16; e[6]=pv2.w&0xffff; e[7]=pv2.w>>16;
      e[8]=pv3.x&0xffff; e[9]=pv3.x>>16; e[10]=pv3.y&0xffff; e[11]=pv3.y>>16;
      e[12]=pv3.z&0xffff; e[13]=pv3.z>>16; e[14]=pv3.w&0xffff; e[15]=pv3.w>>16;
      #pragma unroll
      for (int j=0;j<16;j++) Vts[sc + j][64 + sr] = e[j];
    }
    __syncthreads();

    if (jt2 + 1 < Sz/128) { // prefetch next tile while computing this one
      size_t off0 = ((size_t)(b*Sz + (jt2+1)*128 + sr))*Dz + h*HDz + sc;
      size_t off1 = off0 + (size_t)64*Dz;
      pk0 = *(const uint4*)(Kg + off0); pk1 = *(const uint4*)(Kg + off0 + 8);
      pk2 = *(const uint4*)(Kg + off1); pk3 = *(const uint4*)(Kg + off1 + 8);
      pv0 = *(const uint4*)(Vg + off0); pv1 = *(const uint4*)(Vg + off0 + 8);
      pv2 = *(const uint4*)(Vg + off1); pv3 = *(const uint4*)(Vg + off1 + 8);
    }

    #pragma unroll
    for (int hh=0; hh<2; ++hh){
      // ---- S = Q K^T for this 64-key half ----
      floatx4 acc_s[2][4];
      #pragma unroll
      for (int i=0;i<2;i++)
        #pragma unroll
        for (int j=0;j<4;j++) acc_s[i][j] = (floatx4){0.f,0.f,0.f,0.f};
      #pragma unroll
      for (int ks=0;ks<2;ks++){
        short8 bk[4];
        #pragma unroll
        for (int j=0;j<4;j++) bk[j] = *(const short8*)&Ks[hh*64 + j*16 + l15][ks*32 + quad*8];
        #pragma unroll
        for (int i=0;i<2;i++)
          #pragma unroll
          for (int j=0;j<4;j++)
            acc_s[i][j] = __builtin_amdgcn_mfma_f32_16x16x32_bf16(aq[i][ks], bk[j], acc_s[i][j], 0, 0, 0);
      }
      // ---- p = exp(s); accumulate l; stash P (wave-private LDS rows) ----
      #pragma unroll
      for (int i=0;i<2;i++){
        #pragma unroll
        for (int j=0;j<4;j++){
          int kj = jt2*128 + hh*64 + j*16 + l15;
          #pragma unroll
          for (int r=0;r<4;r++){
            int qrow = qt*128 + wave*32 + i*16 + quad*4 + r;
            float s = acc_s[i][j][r] * 0.125f;
            if (kj <= qrow) s = NEGf;              // faithful-bug mask
            float p = __expf(fminf(s, 80.f));      // exp(-1e9)=0 exactly
            lacc[i][r] += p;
            Ps[wave*32 + i*16 + quad*4 + r][j*16 + l15] = f2bf(p);
          }
        }
      }
      // ---- O += P V (same-wave LDS round-trip; DS ops are wave-ordered) ----
      #pragma unroll
      for (int ks=0;ks<2;ks++){
        short8 ap[2], bv[4];
        #pragma unroll
        for (int i=0;i<2;i++) ap[i] = *(const short8*)&Ps[wave*32 + i*16 + l15][ks*32 + quad*8];
        #pragma unroll
        for (int j=0;j<4;j++) bv[j] = *(const short8*)&Vts[j*16 + l15][hh*64 + ks*32 + quad*8];
        #pragma unroll
        for (int i=0;i<2;i++)
          #pragma unroll
          for (int j=0;j<4;j++)
            acc_o[i][j] = __builtin_amdgcn_mfma_f32_16x16x32_bf16(ap[i], bv[j], acc_o[i][j], 0, 0, 0);
      }
    }
  }

  // ---- epilogue: reduce l across the 16 column-lanes, normalize, write ----
  #pragma unroll
  for (int i=0;i<2;i++){
    #pragma unroll
    for (int r=0;r<4;r++){
      float l = lacc[i][r];
      l += __shfl_xor(l, 1, 64);
      l += __shfl_xor(l, 2, 64);
      l += __shfl_xor(l, 4, 64);
      l += __shfl_xor(l, 8, 64);
      int qrow = qt*128 + wave*32 + i*16 + quad*4 + r;
      float inv = 1.0f / l;                 // row S-1: substituted below
      size_t rowoff = ((size_t)(b*Sz + qrow))*Dz + h*HDz;
      #pragma unroll
      for (int j=0;j<4;j++){
        float ov = acc_o[i][j][r] * inv;
        if (qrow == Sz-1) ov = vmean[(b*Hz + h)*HDz + j*16 + l15];
        Og[rowoff + j*16 + l15] = f2bf(ov);
      }
    }
  }
}

// ---------------------------------------------------------------------------
extern "C" void kernel_launch(void* const* d_in, const int* in_sizes, int n_in,
                              void* d_out, int out_size, void* d_ws, size_t ws_size,
                              hipStream_t stream)
{
  const float* x    = (const float*)d_in[0];
  const float* wq   = (const float*)d_in[1];
  const float* wk   = (const float*)d_in[2];
  const float* wv   = (const float*)d_in[3];
  const float* wo   = (const float*)d_in[4];
  const float* bo   = (const float*)d_in[5];
  const float* ln1g = (const float*)d_in[6];
  const float* ln1b = (const float*)d_in[7];
  const float* ln2g = (const float*)d_in[8];
  const float* ln2b = (const float*)d_in[9];
  const float* w1   = (const float*)d_in[10];
  const float* b1   = (const float*)d_in[11];
  const float* w2   = (const float*)d_in[12];
  const float* b2   = (const float*)d_in[13];
  float* out = (float*)d_out;

  const size_t MB = 1024*1024;
  char* w = (char*)d_ws;
  float*          trunk = (float*)(w);                  //  0..16  fp32 residual
  unsigned short* lnb   = (unsigned short*)(w + 16*MB); // 16..24  bf16 LN/a2
  float*          vmean = (float*)(w + 16*MB);          // head of lnb (dead there)
  unsigned short* q     = (unsigned short*)(w + 24*MB); // q,k,v contiguous 8 MB regions
  unsigned short* k     = (unsigned short*)(w + 32*MB);
  unsigned short* v     = (unsigned short*)(w + 40*MB);
  unsigned short* ctx   = (unsigned short*)(w + 48*MB);
  unsigned short* wqkvT = (unsigned short*)(w + 56*MB); // wq/wk/wv T concat [3072][1024]
  unsigned short* wqT   = wqkvT;
  unsigned short* wkT   = (unsigned short*)(w + 58*MB);
  unsigned short* wvT   = (unsigned short*)(w + 60*MB);
  unsigned short* woT   = (unsigned short*)(w + 62*MB);
  unsigned short* w1T   = (unsigned short*)(w + 64*MB); // [F][D] 8 MB
  unsigned short* w2T   = (unsigned short*)(w + 72*MB); // [D][F] 8 MB
  unsigned short* mid   = (unsigned short*)(w + 24*MB); // overlap: q/k/v/ctx dead
  float*          part  = (float*)(w + 80*MB);          // 64 MB split-K partials
  bool splitk = ws_size >= (size_t)144*MB;

  dim3 blk(256), blk512(512);
  transpose_cast<<<dim3(32,32),  blk, 0, stream>>>(wq, wqT, Dz, Dz);
  transpose_cast<<<dim3(32,32),  blk, 0, stream>>>(wk, wkT, Dz, Dz);
  transpose_cast<<<dim3(32,32),  blk, 0, stream>>>(wv, wvT, Dz, Dz);
  transpose_cast<<<dim3(32,32),  blk, 0, stream>>>(wo, woT, Dz, Dz);
  transpose_cast<<<dim3(128,32), blk, 0, stream>>>(w1, w1T, Dz, Fz);
  transpose_cast<<<dim3(32,128), blk, 0, stream>>>(w2, w2T, Fz, Dz);

  dim3 gln(ROWS);
  dim3 gqkv(3*Dz/256, ROWS/256);  // (12,16) fused QKV, 256^2 tiles
  dim3 gf1(Fz/256,  ROWS/256);    // (16,16) ffn1
  dim3 gn64(Dz/64,  ROWS/128);    // (16,32) = 512 blocks, 2/CU
  dim3 gattn(Sz/128, Hz, Bz);
  dim3 gvm(Hz, Bz);

  // ---- block 1: h = attn(LN1(x)) + x ----
  ln_kernel<<<gln, blk, 0, stream>>>(x, ln1g, ln1b, lnb);
  gemm256<<<gqkv, blk512, 0, stream>>>(lnb, wqkvT, nullptr, nullptr, nullptr, q, ROWS, 3*Dz, Dz, Dz, Dz, 0, 1);
  vmean_kernel<<<gvm, blk, 0, stream>>>(v, vmean);
  attn_mfma<<<gattn, blk, 0, stream>>>(q, k, v, vmean, ctx);
  gemm_n64<<<gn64, blk, 0, stream>>>(ctx, woT, bo, x, trunk, nullptr, ROWS, Dz, Dz);

  // ---- block 2: out = ffn(attn(LN2(h))) + h ----
  ln_kernel<<<gln, blk, 0, stream>>>(trunk, ln2g, ln2b, lnb);
  gemm256<<<gqkv, blk512, 0, stream>>>(lnb, wqkvT, nullptr, nullptr, nullptr, q, ROWS, 3*Dz, Dz, Dz, Dz, 0, 1);
  vmean_kernel<<<gvm, blk, 0, stream>>>(v, vmean);
  attn_mfma<<<gattn, blk, 0, stream>>>(q, k, v, vmean, ctx);
  gemm_n64<<<gn64, blk, 0, stream>>>(ctx, woT, bo, nullptr, nullptr, lnb, ROWS, Dz, Dz);
  gemm256<<<gf1, blk512, 0, stream>>>(lnb, w1T, b1, nullptr, nullptr, mid, ROWS, Fz, Dz, Dz, Dz, 1, 0);
  if (splitk) {
    gemm256<<<dim3(4,16,4), blk512, 0, stream>>>(mid, w2T, nullptr, nullptr, part, nullptr, ROWS, Dz, Fz/4, Fz, Fz, 0, 0);
    reduce4<<<dim3(4096), blk, 0, stream>>>(part, b2, trunk, out);
  } else {
    gemm_n64<<<gn64, blk, 0, stream>>>(mid, w2T, b2, trunk, out, nullptr, ROWS, Dz, Fz);
  }
}

// Round 2
// 537.528 us; speedup vs baseline: 1.0048x; 1.0048x over previous
//
#include <hip/hip_runtime.h>
#include <hip/hip_bf16.h>
#include <math.h>

#define Bz 2
#define Sz 2048
#define Dz 1024
#define Hz 16
#define HDz 64
#define Fz 4096
#define ROWS (Bz*Sz)          // 4096
#define EPSf 1e-5f
#define NEGf -1e9f

typedef __attribute__((ext_vector_type(8))) short short8;   // 8 bf16 (4 VGPRs)
typedef __attribute__((ext_vector_type(4))) float floatx4;  // MFMA C/D

__device__ __forceinline__ unsigned short f2bf(float f){
  __hip_bfloat16 h = __float2bfloat16(f);
  return *(unsigned short*)&h;
}
__device__ __forceinline__ float bf2f(unsigned short u){
  union { unsigned x; float f; } a; a.x = ((unsigned)u) << 16; return a.f;
}

// exact-accuracy gelu via A&S 7.1.26 erf (|err|<=1.5e-7)
__device__ __forceinline__ float fast_gelu(float x){
  float t  = fabsf(x) * 0.70710678118654752f;
  float kk = __builtin_amdgcn_rcpf(1.0f + 0.3275911f * t);
  float poly = ((((1.061405429f*kk - 1.453152027f)*kk + 1.421413741f)*kk
                 - 0.284496736f)*kk + 0.254829592f)*kk;
  float er = 1.0f - poly * __expf(-t*t);
  er = copysignf(er, x);
  return 0.5f * x * (1.0f + er);
}

// async global->LDS, 16 B per lane, LDS dest = wave-uniform base + lane*16
__device__ __forceinline__ void gload16(const void* g, void* l){
  __builtin_amdgcn_global_load_lds(
      (const __attribute__((address_space(1))) unsigned int*)g,
      (__attribute__((address_space(3))) unsigned int*)l, 16, 0, 0);
}

// raw barrier (no implicit vmcnt(0) drain, unlike __syncthreads)
__device__ __forceinline__ void bar(){
  asm volatile("" ::: "memory");
  __builtin_amdgcn_s_barrier();
  asm volatile("" ::: "memory");
}
#define WAITV6 asm volatile("s_waitcnt vmcnt(6)" ::: "memory")
#define WAITV0 asm volatile("s_waitcnt vmcnt(0)" ::: "memory")
#define WL0    asm volatile("s_waitcnt lgkmcnt(0)" ::: "memory")

// XCD-clustered block remap (used by gemm_n64)
__device__ __forceinline__ void xcd_remap(int& bmblk, int& bnblk){
  int gx = gridDim.x, gy = gridDim.y;
  int id = blockIdx.y * gx + blockIdx.x;
  int xcd = id & 7, local = id >> 3;
  bnblk = local % gx;
  bmblk = xcd * (gy >> 3) + local / gx;
}

// ---------------- weight transpose + fp32->bf16 cast: W[K][N] -> Wt[N][K] ---
__global__ __launch_bounds__(256)
void transpose_cast(const float* __restrict__ W, unsigned short* __restrict__ Wt,
                    int K, int N)
{
  __shared__ unsigned short Ts[32][33];
  int n0 = blockIdx.x*32, k0 = blockIdx.y*32;
  int r = threadIdx.x >> 3, c0 = (threadIdx.x & 7) * 4;
  float4 w4 = *(const float4*)(W + (size_t)(k0+r)*N + n0 + c0);
  Ts[r][c0+0] = f2bf(w4.x); Ts[r][c0+1] = f2bf(w4.y);
  Ts[r][c0+2] = f2bf(w4.z); Ts[r][c0+3] = f2bf(w4.w);
  __syncthreads();
  unsigned v0 = Ts[c0+0][r], v1 = Ts[c0+1][r], v2 = Ts[c0+2][r], v3 = Ts[c0+3][r];
  uint2 p; p.x = v0 | (v1<<16); p.y = v2 | (v3<<16);
  *(uint2*)(Wt + (size_t)(n0+r)*K + k0 + c0) = p;
}

// ---------------- V transpose (bf16): v[b][s][h*64+d] -> vT[(b*16+h)*64+d][s]
__global__ __launch_bounds__(256)
void transpose_bf(const unsigned short* __restrict__ V, unsigned short* __restrict__ VT)
{
  __shared__ unsigned short Ts[32][33];
  int st = blockIdx.x*32;           // s-tile
  int R0 = blockIdx.y*32;           // output-row tile (R = (b*16+h)*64+d)
  int b = R0 >> 10, hd0 = R0 & 1023;
  int r = threadIdx.x >> 3, c0 = (threadIdx.x & 7) * 4;
  uint2 w = *(const uint2*)(V + (size_t)(b*Sz + st + r)*Dz + hd0 + c0);
  Ts[r][c0+0] = (unsigned short)(w.x & 0xffff);
  Ts[r][c0+1] = (unsigned short)(w.x >> 16);
  Ts[r][c0+2] = (unsigned short)(w.y & 0xffff);
  Ts[r][c0+3] = (unsigned short)(w.y >> 16);
  __syncthreads();
  unsigned v0 = Ts[c0+0][r], v1 = Ts[c0+1][r], v2 = Ts[c0+2][r], v3 = Ts[c0+3][r];
  uint2 p; p.x = v0 | (v1<<16); p.y = v2 | (v3<<16);
  *(uint2*)(VT + (size_t)(R0+r)*Sz + st + c0) = p;
}

// ---------------- LayerNorm: fp32 in -> bf16 out, one block per row --------
__global__ __launch_bounds__(256)
void ln_kernel(const float* __restrict__ in, const float* __restrict__ gam,
               const float* __restrict__ bet, unsigned short* __restrict__ out)
{
  int row = blockIdx.x, t = threadIdx.x;
  size_t base = (size_t)row * Dz;
  int c0 = t * 4;
  float4 x4 = *(const float4*)(in + base + c0);
  float v[4] = {x4.x, x4.y, x4.z, x4.w};
  float s = v[0]+v[1]+v[2]+v[3];
  #pragma unroll
  for (int off=32; off>0; off>>=1) s += __shfl_down(s, off, 64);
  __shared__ float ws[4];
  int lane = t & 63, wid = t >> 6;
  if (lane == 0) ws[wid] = s;
  __syncthreads();
  float mu = (ws[0]+ws[1]+ws[2]+ws[3]) * (1.0f/Dz);
  __syncthreads();
  float d0=v[0]-mu, d1=v[1]-mu, d2=v[2]-mu, d3=v[3]-mu;
  float s2 = d0*d0+d1*d1+d2*d2+d3*d3;
  #pragma unroll
  for (int off=32; off>0; off>>=1) s2 += __shfl_down(s2, off, 64);
  if (lane == 0) ws[wid] = s2;
  __syncthreads();
  float var = (ws[0]+ws[1]+ws[2]+ws[3]) * (1.0f/Dz);
  float rstd = rsqrtf(var + EPSf);
  float4 g4 = *(const float4*)(gam + c0);
  float4 b4 = *(const float4*)(bet + c0);
  unsigned r0 = f2bf((v[0]-mu)*rstd*g4.x + b4.x);
  unsigned r1 = f2bf((v[1]-mu)*rstd*g4.y + b4.y);
  unsigned r2 = f2bf((v[2]-mu)*rstd*g4.z + b4.z);
  unsigned r3 = f2bf((v[3]-mu)*rstd*g4.w + b4.w);
  uint2 p; p.x = r0 | (r1<<16); p.y = r2 | (r3<<16);
  *(uint2*)(out + base + c0) = p;
}

// ===========================================================================
// 256x256-tile, BK=64, 8-wave, 8-phase GEMM (HK-style schedule, plain HIP).
// (unchanged from previous round — verified)
// ===========================================================================
#define STG_A(buf, half, k0) { \
  _Pragma("unroll") for (int c_=0;c_<2;c_++){ \
    int sg_ = c_*8 + wave; \
    int row0_ = ((sg_>>3)<<7) + ((sg_&7)<<3) + ((half)<<6); \
    gload16(pA[half][c_] + (k0), &As[buf][row0_*64]); } }

#define STG_B(buf, jh, k0) { \
  _Pragma("unroll") for (int c_=0;c_<2;c_++){ \
    int sg_ = c_*8 + wave; int rho0_ = sg_<<3; \
    gload16(pB[jh][c_] + (k0), &Bs[buf][jh][rho0_*64]); } }

#define READ_A4(dst, buf, ihalf) { \
  _Pragma("unroll") for (int ii_=0; ii_<4; ++ii_){ \
    int row_ = wm*128 + ((ihalf)*4+ii_)*16 + l15; \
    _Pragma("unroll") for (int ks_=0; ks_<2; ++ks_){ \
      int slot_ = (ks_*4+quad) ^ (l15&7); \
      dst[ii_][ks_] = *(const short8*)&As[buf][row_*64 + slot_*8]; } } }

#define READ_B2(dst, buf, jh) { \
  _Pragma("unroll") for (int jl_=0; jl_<2; ++jl_){ \
    int rho_ = wn*32 + jl_*16 + l15; \
    _Pragma("unroll") for (int ks_=0; ks_<2; ++ks_){ \
      int slot_ = (ks_*4+quad) ^ (l15&7); \
      dst[jl_][ks_] = *(const short8*)&Bs[buf][jh][rho_*64 + slot_*8]; } } }

#define MFMA_PH(IH, JH, AF, BF) { \
  __builtin_amdgcn_s_setprio(1); \
  _Pragma("unroll") for (int ii_=0; ii_<4; ++ii_){ \
    _Pragma("unroll") for (int jl_=0; jl_<2; ++jl_){ \
      floatx4 c_ = acc[(IH)*4+ii_][(JH)*2+jl_]; \
      c_ = __builtin_amdgcn_mfma_f32_16x16x32_bf16(AF[ii_][0], BF[jl_][0], c_, 0,0,0); \
      c_ = __builtin_amdgcn_mfma_f32_16x16x32_bf16(AF[ii_][1], BF[jl_][1], c_, 0,0,0); \
      acc[(IH)*4+ii_][(JH)*2+jl_] = c_; } } \
  __builtin_amdgcn_s_setprio(0); }

__global__ __launch_bounds__(512, 2)
void gemm256(const unsigned short* __restrict__ A,
             const unsigned short* __restrict__ Bt,
             const float* __restrict__ bias, const float* __restrict__ res,
             float* __restrict__ outf, unsigned short* __restrict__ outb,
             int M, int N, int K, int lda, int ldb, int act, int qkvmode)
{
  __shared__ unsigned short As[2][256*64];     // [buf][row(256)][k(64)], swizzled slots
  __shared__ unsigned short Bs[2][2][128*64];  // [buf][jh][wn*32+jl*16+l15][k(64)]

  int t = threadIdx.x;
  int wave = t >> 6, lane = t & 63;
  int l15 = lane & 15, quad = lane >> 4;
  int wm = wave >> 2, wn = wave & 3;           // 2x4 wave grid, wave tile 128x64

  // bijective XCD-clustered remap (requires gridDim.y % 8 == 0)
  int nN = gridDim.x, nM = gridDim.y;
  int id = blockIdx.y * nN + blockIdx.x;
  int xcd = id & 7, local = id >> 3;
  int bnblk = local % nN;
  int bmblk = xcd * (nM >> 3) + local / nN;
  int bm = bmblk * 256, bn = bnblk * 256;

  if (gridDim.z > 1){
    A    += (size_t)blockIdx.z * K;
    Bt   += (size_t)blockIdx.z * K;
    outf += (size_t)blockIdx.z * ((size_t)M * N);
  }

  int lrow = lane >> 3;                         // 0..7 rows within a 1KB piece
  int lcol = ((lane & 7) ^ (lane >> 3)) * 8;    // inverse-swizzled source chunk

  const unsigned short* pA[2][2];
  const unsigned short* pB[2][2];
  #pragma unroll
  for (int half=0; half<2; half++)
    #pragma unroll
    for (int c=0;c<2;c++){
      int sg = c*8 + wave;
      int row0 = ((sg>>3)<<7) + ((sg&7)<<3) + (half<<6);
      pA[half][c] = A + (size_t)(bm + row0 + lrow)*lda + lcol;
    }
  #pragma unroll
  for (int jh=0; jh<2; jh++)
    #pragma unroll
    for (int c=0;c<2;c++){
      int sg = c*8 + wave;
      int rho0 = sg<<3;
      int gn = ((rho0>>5)<<6) + (jh<<5) + (rho0&31);
      pB[jh][c] = Bt + (size_t)(bn + gn + lrow)*ldb + lcol;
    }

  floatx4 acc[8][4];
  #pragma unroll
  for (int i=0;i<8;i++)
    #pragma unroll
    for (int j=0;j<4;j++) acc[i][j] = (floatx4){0.f,0.f,0.f,0.f};

  STG_A(0, 0, 0);  STG_A(0, 1, 0);
  STG_B(0, 0, 0);  STG_B(0, 1, 0);
  STG_A(1, 0, 64); STG_A(1, 1, 64);
  STG_B(1, 0, 64);
  WAITV6;
  bar();

  int NKT = K >> 6;
  int nIter = NKT >> 1;
  for (int it = 0; it < nIter; ++it){
    bool more = (it + 1 < nIter);
    int k0B  = (2*it+1) << 6;
    int k0A2 = (2*it+2) << 6;
    int k0B2 = (2*it+3) << 6;
    short8 aLo[4][2], aHi[4][2], bcur[2][2];

    READ_A4(aLo, 0, 0);
    READ_B2(bcur, 0, 0);
    STG_B(1, 1, k0B);
    bar(); WL0;
    MFMA_PH(0, 0, aLo, bcur);
    bar();

    READ_A4(aHi, 0, 1);
    READ_B2(bcur, 0, 0);
    if (more) STG_A(0, 0, k0A2);
    bar(); WL0;
    MFMA_PH(1, 0, aHi, bcur);
    bar();

    READ_B2(bcur, 0, 1);
    if (more) STG_A(0, 1, k0A2);
    bar(); WL0;
    MFMA_PH(0, 1, aLo, bcur);
    bar();

    if (more) { STG_B(0, 0, k0A2); WAITV6; }
    else      { WAITV0; }
    bar();
    MFMA_PH(1, 1, aHi, bcur);
    bar();

    READ_A4(aLo, 1, 0);
    READ_B2(bcur, 1, 0);
    if (more) STG_B(0, 1, k0A2);
    bar(); WL0;
    MFMA_PH(0, 0, aLo, bcur);
    bar();

    READ_A4(aHi, 1, 1);
    READ_B2(bcur, 1, 0);
    if (more) STG_A(1, 0, k0B2);
    bar(); WL0;
    MFMA_PH(1, 0, aHi, bcur);
    bar();

    READ_B2(bcur, 1, 1);
    if (more) STG_A(1, 1, k0B2);
    bar(); WL0;
    MFMA_PH(0, 1, aLo, bcur);
    bar();

    if (more) { STG_B(1, 0, k0B2); WAITV6; }
    bar();
    MFMA_PH(1, 1, aHi, bcur);
    bar();
  }

  float bj[4];
  #pragma unroll
  for (int j=0;j<4;j++) bj[j] = bias ? bias[bn + wn*64 + j*16 + l15] : 0.f;

  size_t selbase = 0; int ncol = N; int bnl = bn;
  if (qkvmode){ selbase = (size_t)(bn >> 10) * ((size_t)M * 1024); ncol = 1024; bnl = bn & 1023; }

  #pragma unroll
  for (int i=0;i<8;i++){
    int row0 = bm + wm*128 + i*16 + quad*4;
    #pragma unroll
    for (int r=0;r<4;r++){
      size_t rowoff = selbase + (size_t)(row0 + r) * ncol;
      #pragma unroll
      for (int j=0;j<4;j++){
        float v = acc[i][j][r] + bj[j];
        if (act) v = fast_gelu(v);
        size_t off = rowoff + bnl + wn*64 + j*16 + l15;
        if (res) v += res[off];
        if (outf) outf[off] = v;
        else      outb[off] = f2bf(v);
      }
    }
  }
}

// ---------------- MFMA GEMM 128x64, BK=64, double-buffered ------------------
__global__ __launch_bounds__(256)
void gemm_n64(const unsigned short* __restrict__ A,
              const unsigned short* __restrict__ Bt,
              const float* __restrict__ bias, const float* __restrict__ res,
              float* __restrict__ outf, unsigned short* __restrict__ outb,
              int M, int N, int K)
{
  __shared__ unsigned short As[2][128*64];   // [m][k], swizzled blocks
  __shared__ unsigned short Bs[2][64*64];    // [n][k]
  int t = threadIdx.x;
  int bmblk, bnblk; xcd_remap(bmblk, bnblk);
  int bm = bmblk * 128, bn = bnblk * 64;
  int wave = t >> 6, lane = t & 63;
  int l15 = lane & 15, quad = lane >> 4;
  int arow = lane >> 3;
  int acbg = ((lane & 7) ^ arow) * 8;
  const unsigned short* gA = A  + (size_t)(bm + wave*32 + arow)*K + acbg;
  const unsigned short* gB = Bt + (size_t)(bn + wave*16 + arow)*K + acbg;

  floatx4 acc[2][4];
  #pragma unroll
  for (int i=0;i<2;i++)
    #pragma unroll
    for (int j=0;j<4;j++) acc[i][j] = (floatx4){0.f,0.f,0.f,0.f};

  int swr = (l15 & 7);   // read-side XOR key

  { // prologue: tile 0 -> buffer 0
    unsigned short* lA = &As[0][wave*32*64];
    unsigned short* lB = &Bs[0][wave*16*64];
    gload16(gA,                 lA);
    gload16(gA + (size_t)8*K,   lA + 8*64);
    gload16(gA + (size_t)16*K,  lA + 16*64);
    gload16(gA + (size_t)24*K,  lA + 24*64);
    gload16(gB,                 lB);
    gload16(gB + (size_t)8*K,   lB + 8*64);
  }

  int nIter = K >> 6;
  for (int it = 0; it < nIter; ++it) {
    __syncthreads();
    int cur = it & 1;
    if (it + 1 < nIter) {
      int k1 = (it+1) << 6;
      unsigned short* lA = &As[cur^1][wave*32*64];
      unsigned short* lB = &Bs[cur^1][wave*16*64];
      gload16(gA + k1,                 lA);
      gload16(gA + k1 + (size_t)8*K,   lA + 8*64);
      gload16(gA + k1 + (size_t)16*K,  lA + 16*64);
      gload16(gA + k1 + (size_t)24*K,  lA + 24*64);
      gload16(gB + k1,                 lB);
      gload16(gB + k1 + (size_t)8*K,   lB + 8*64);
    }
    const unsigned short* Ac = As[cur];
    const unsigned short* Bc = Bs[cur];
    #pragma unroll
    for (int ks=0; ks<2; ++ks){
      short8 af[2], bf[4];
      #pragma unroll
      for (int i=0;i<2;i++)
        af[i] = *(const short8*)&Ac[(wave*32 + i*16 + l15)*64 + ((ks*4 + quad) ^ swr)*8];
      #pragma unroll
      for (int j=0;j<4;j++)
        bf[j] = *(const short8*)&Bc[(j*16 + l15)*64 + ((ks*4 + quad) ^ swr)*8];
      #pragma unroll
      for (int i=0;i<2;i++)
        #pragma unroll
        for (int j=0;j<4;j++)
          acc[i][j] = __builtin_amdgcn_mfma_f32_16x16x32_bf16(af[i], bf[j], acc[i][j], 0, 0, 0);
    }
  }

  float bj[4];
  #pragma unroll
  for (int j=0;j<4;j++) bj[j] = bias ? bias[bn + j*16 + l15] : 0.f;

  #pragma unroll
  for (int i=0;i<2;i++){
    int row0 = bm + wave*32 + i*16 + quad*4;
    #pragma unroll
    for (int r=0;r<4;r++){
      size_t rowoff = (size_t)(row0 + r) * N;
      #pragma unroll
      for (int j=0;j<4;j++){
        float v = acc[i][j][r] + bj[j];
        size_t off = rowoff + bn + j*16 + l15;
        if (res) v += res[off];
        if (outf) outf[off] = v;
        else      outb[off] = f2bf(v);
      }
    }
  }
}

// ---------------- split-K reduce: out = sum(part[0..3]) + bias + res --------
__global__ __launch_bounds__(256)
void reduce4(const float* __restrict__ part, const float* __restrict__ bias,
             const float* __restrict__ res, float* __restrict__ out)
{
  const size_t NN = (size_t)ROWS * Dz;
  size_t i = ((size_t)blockIdx.x * 256 + threadIdx.x) * 4;  // one block per row
  float4 a = *(const float4*)(part + i);
  float4 b = *(const float4*)(part + NN + i);
  float4 c = *(const float4*)(part + 2*NN + i);
  float4 d = *(const float4*)(part + 3*NN + i);
  float4 r = *(const float4*)(res + i);
  int col = threadIdx.x * 4;
  float4 g = *(const float4*)(bias + col);
  float4 o;
  o.x = a.x+b.x+c.x+d.x + g.x + r.x;
  o.y = a.y+b.y+c.y+d.y + g.y + r.y;
  o.z = a.z+b.z+c.z+d.z + g.z + r.z;
  o.w = a.w+b.w+c.w+d.w + g.w + r.w;
  *(float4*)(out + i) = o;
}

// ---------------- V column-mean per (b,h): for the all-masked row S-1 -------
__global__ __launch_bounds__(256)
void vmean_kernel(const unsigned short* __restrict__ v, float* __restrict__ vm)
{
  int h = blockIdx.x, b = blockIdx.y;
  int t = threadIdx.x, d = t & 63, seg = t >> 6;
  float s = 0.f;
  for (int i=0;i<512;i++){
    int srow = seg*512 + i;
    s += bf2f(v[((size_t)(b*Sz + srow))*Dz + h*HDz + d]);
  }
  __shared__ float red[4][64];
  red[seg][d] = s;
  __syncthreads();
  if (seg == 0){
    float tot = red[0][d]+red[1][d]+red[2][d]+red[3][d];
    vm[(b*Hz + h)*HDz + d] = tot * (1.0f/2048.0f);
  }
}

// ---------------- MFMA flash attention v2 ----------------------------------
// Changes vs v1: (a) V consumed pre-transposed (vT[(b*16+h)*64+d][s]) -> LDS
// staging is 4 clean uint4 writes/lane with the gemm-verified XOR chunk
// swizzle (kills the 8-way-conflict scalar transpose + its VALU unpack);
// (b) K tile moves to swizzled [128][64] (same pattern);
// (c) LDS 54.3KB -> 51.2KB => 3 blocks/CU (was 2).
__global__ __launch_bounds__(256)
void attn_mfma(const unsigned short* __restrict__ Qg,
               const unsigned short* __restrict__ Kg,
               const unsigned short* __restrict__ VTg,
               const float* __restrict__ vmean,
               unsigned short* __restrict__ Og)
{
  __shared__ unsigned short Ks[128*64];    // [key][d], XOR-swizzled 8-chunks
  __shared__ unsigned short Vts[64*128];   // [d][key], XOR-swizzled 8-chunks
  __shared__ unsigned short Ps[128][72];   // Q staging, then P (wave-private rows)

  int t = threadIdx.x;
  int wave = t >> 6, lane = t & 63;
  int l15 = lane & 15, quad = lane >> 4;
  int b = blockIdx.z, h = blockIdx.y;
  int qt = b ? (15 - (int)blockIdx.x) : (int)blockIdx.x;   // load-balance pairing

  { // stage Q tile (128 x 64) into Ps; wave w writes exactly rows 32w..32w+31
    int r = t >> 1, c = (t & 1) * 32;
    const unsigned short* qp = Qg + ((size_t)(b*Sz + qt*128 + r))*Dz + h*HDz + c;
    uint4 q0 = *(const uint4*)(qp);
    uint4 q1 = *(const uint4*)(qp + 8);
    uint4 q2 = *(const uint4*)(qp + 16);
    uint4 q3 = *(const uint4*)(qp + 24);
    *(uint4*)&Ps[r][c]      = q0;
    *(uint4*)&Ps[r][c + 8]  = q1;
    *(uint4*)&Ps[r][c + 16] = q2;
    *(uint4*)&Ps[r][c + 24] = q3;
  }
  __syncthreads();
  short8 aq[2][2];
  #pragma unroll
  for (int i=0;i<2;i++)
    #pragma unroll
    for (int ks=0;ks<2;ks++)
      aq[i][ks] = *(const short8*)&Ps[wave*32 + i*16 + l15][ks*32 + quad*8];

  floatx4 acc_o[2][4];
  #pragma unroll
  for (int i=0;i<2;i++)
    #pragma unroll
    for (int j=0;j<4;j++) acc_o[i][j] = (floatx4){0.f,0.f,0.f,0.f};
  float lacc[2][4];
  #pragma unroll
  for (int i=0;i<2;i++)
    #pragma unroll
    for (int r=0;r<4;r++) lacc[i][r] = 0.f;

  // K staging coords: row sr (and 64+sr), chunks 2c,2c+1 (c = t&3)
  int sr = t >> 2, sc = (t & 3) * 16;
  int kc2 = (t & 3) * 2, ksw = sr & 7;
  // V^T staging coords: row vd, key-chunks vc*4..vc*4+3
  int vd = t >> 2, vc = t & 3, vsw = vd & 7;
  const unsigned short* vrow = VTg + ((size_t)((b*Hz + h)*64 + vd))*Sz;

  uint4 pk0,pk1,pk2,pk3,pv0,pv1,pv2,pv3;
  { // preload first tile into registers
    size_t off0 = ((size_t)(b*Sz + qt*128 + sr))*Dz + h*HDz + sc;
    size_t off1 = off0 + (size_t)64*Dz;
    pk0 = *(const uint4*)(Kg + off0); pk1 = *(const uint4*)(Kg + off0 + 8);
    pk2 = *(const uint4*)(Kg + off1); pk3 = *(const uint4*)(Kg + off1 + 8);
    int vo = qt*128 + vc*32;
    pv0 = *(const uint4*)(vrow + vo);      pv1 = *(const uint4*)(vrow + vo + 8);
    pv2 = *(const uint4*)(vrow + vo + 16); pv3 = *(const uint4*)(vrow + vo + 24);
  }

  for (int jt2 = qt; jt2 < Sz/128; ++jt2) {
    __syncthreads();
    { // stage K tile (swizzled uint4 writes)
      *(uint4*)&Ks[sr*64      + ((kc2  ) ^ ksw)*8] = pk0;
      *(uint4*)&Ks[sr*64      + ((kc2+1) ^ ksw)*8] = pk1;
      *(uint4*)&Ks[(64+sr)*64 + ((kc2  ) ^ ksw)*8] = pk2;
      *(uint4*)&Ks[(64+sr)*64 + ((kc2+1) ^ ksw)*8] = pk3;
      // stage V^T tile (swizzled uint4 writes); k8 in 0..15, keep high bit
      int k80 = vc*4;
      *(uint4*)&Vts[vd*128 + (((k80+0)&8) | (((k80+0)^vsw)&7))*8] = pv0;
      *(uint4*)&Vts[vd*128 + (((k80+1)&8) | (((k80+1)^vsw)&7))*8] = pv1;
      *(uint4*)&Vts[vd*128 + (((k80+2)&8) | (((k80+2)^vsw)&7))*8] = pv2;
      *(uint4*)&Vts[vd*128 + (((k80+3)&8) | (((k80+3)^vsw)&7))*8] = pv3;
    }
    __syncthreads();

    if (jt2 + 1 < Sz/128) { // prefetch next tile while computing this one
      size_t off0 = ((size_t)(b*Sz + (jt2+1)*128 + sr))*Dz + h*HDz + sc;
      size_t off1 = off0 + (size_t)64*Dz;
      pk0 = *(const uint4*)(Kg + off0); pk1 = *(const uint4*)(Kg + off0 + 8);
      pk2 = *(const uint4*)(Kg + off1); pk3 = *(const uint4*)(Kg + off1 + 8);
      int vo = (jt2+1)*128 + vc*32;
      pv0 = *(const uint4*)(vrow + vo);      pv1 = *(const uint4*)(vrow + vo + 8);
      pv2 = *(const uint4*)(vrow + vo + 16); pv3 = *(const uint4*)(vrow + vo + 24);
    }

    #pragma unroll
    for (int hh=0; hh<2; ++hh){
      // ---- S = Q K^T for this 64-key half ----
      floatx4 acc_s[2][4];
      #pragma unroll
      for (int i=0;i<2;i++)
        #pragma unroll
        for (int j=0;j<4;j++) acc_s[i][j] = (floatx4){0.f,0.f,0.f,0.f};
      #pragma unroll
      for (int ks=0;ks<2;ks++){
        short8 bk[4];
        #pragma unroll
        for (int j=0;j<4;j++)
          bk[j] = *(const short8*)&Ks[(hh*64 + j*16 + l15)*64 + (((ks*4+quad) ^ (l15&7)))*8];
        #pragma unroll
        for (int i=0;i<2;i++)
          #pragma unroll
          for (int j=0;j<4;j++)
            acc_s[i][j] = __builtin_amdgcn_mfma_f32_16x16x32_bf16(aq[i][ks], bk[j], acc_s[i][j], 0, 0, 0);
      }
      // ---- p = exp(s); accumulate l; stash P (wave-private LDS rows) ----
      #pragma unroll
      for (int i=0;i<2;i++){
        #pragma unroll
        for (int j=0;j<4;j++){
          int kj = jt2*128 + hh*64 + j*16 + l15;
          #pragma unroll
          for (int r=0;r<4;r++){
            int qrow = qt*128 + wave*32 + i*16 + quad*4 + r;
            float s = acc_s[i][j][r] * 0.125f;
            if (kj <= qrow) s = NEGf;              // faithful-bug mask
            float p = __expf(fminf(s, 80.f));      // exp(-1e9)=0 exactly
            lacc[i][r] += p;
            Ps[wave*32 + i*16 + quad*4 + r][j*16 + l15] = f2bf(p);
          }
        }
      }
      // ---- O += P V (same-wave LDS round-trip; DS ops are wave-ordered) ----
      #pragma unroll
      for (int ks=0;ks<2;ks++){
        short8 ap[2], bv[4];
        #pragma unroll
        for (int i=0;i<2;i++) ap[i] = *(const short8*)&Ps[wave*32 + i*16 + l15][ks*32 + quad*8];
        #pragma unroll
        for (int j=0;j<4;j++)
          bv[j] = *(const short8*)&Vts[(j*16 + l15)*128 + (hh*8 + ((ks*4+quad) ^ (l15&7)))*8];
        #pragma unroll
        for (int i=0;i<2;i++)
          #pragma unroll
          for (int j=0;j<4;j++)
            acc_o[i][j] = __builtin_amdgcn_mfma_f32_16x16x32_bf16(ap[i], bv[j], acc_o[i][j], 0, 0, 0);
      }
    }
  }

  // ---- epilogue: reduce l across the 16 column-lanes, normalize, write ----
  #pragma unroll
  for (int i=0;i<2;i++){
    #pragma unroll
    for (int r=0;r<4;r++){
      float l = lacc[i][r];
      l += __shfl_xor(l, 1, 64);
      l += __shfl_xor(l, 2, 64);
      l += __shfl_xor(l, 4, 64);
      l += __shfl_xor(l, 8, 64);
      int qrow = qt*128 + wave*32 + i*16 + quad*4 + r;
      float inv = 1.0f / l;                 // row S-1: substituted below
      size_t rowoff = ((size_t)(b*Sz + qrow))*Dz + h*HDz;
      #pragma unroll
      for (int j=0;j<4;j++){
        float ov = acc_o[i][j][r] * inv;
        if (qrow == Sz-1) ov = vmean[(b*Hz + h)*HDz + j*16 + l15];
        Og[rowoff + j*16 + l15] = f2bf(ov);
      }
    }
  }
}

// ---------------------------------------------------------------------------
extern "C" void kernel_launch(void* const* d_in, const int* in_sizes, int n_in,
                              void* d_out, int out_size, void* d_ws, size_t ws_size,
                              hipStream_t stream)
{
  const float* x    = (const float*)d_in[0];
  const float* wq   = (const float*)d_in[1];
  const float* wk   = (const float*)d_in[2];
  const float* wv   = (const float*)d_in[3];
  const float* wo   = (const float*)d_in[4];
  const float* bo   = (const float*)d_in[5];
  const float* ln1g = (const float*)d_in[6];
  const float* ln1b = (const float*)d_in[7];
  const float* ln2g = (const float*)d_in[8];
  const float* ln2b = (const float*)d_in[9];
  const float* w1   = (const float*)d_in[10];
  const float* b1   = (const float*)d_in[11];
  const float* w2   = (const float*)d_in[12];
  const float* b2   = (const float*)d_in[13];
  float* out = (float*)d_out;

  const size_t MB = 1024*1024;
  char* w = (char*)d_ws;
  float*          trunk = (float*)(w);                  //  0..16  fp32 residual
  unsigned short* lnb   = (unsigned short*)(w + 16*MB); // 16..24  bf16 LN/a2
  unsigned short* q     = (unsigned short*)(w + 24*MB); // q,k,v contiguous 8 MB regions
  unsigned short* k     = (unsigned short*)(w + 32*MB);
  unsigned short* v     = (unsigned short*)(w + 40*MB);
  unsigned short* ctx   = (unsigned short*)(w + 48*MB);
  unsigned short* wqkvT = (unsigned short*)(w + 56*MB); // wq/wk/wv T concat [3072][1024]
  unsigned short* wqT   = wqkvT;
  unsigned short* wkT   = (unsigned short*)(w + 58*MB);
  unsigned short* wvT   = (unsigned short*)(w + 60*MB);
  unsigned short* woT   = (unsigned short*)(w + 62*MB);
  unsigned short* w1T   = (unsigned short*)(w + 64*MB); // [F][D] 8 MB
  unsigned short* w2T   = (unsigned short*)(w + 72*MB); // [D][F] 8 MB
  unsigned short* mid   = (unsigned short*)(w + 24*MB); // overlap: q/k/v/ctx dead
  float*          part  = (float*)(w + 80*MB);          // 64 MB split-K partials
  bool splitk = ws_size >= (size_t)144*MB;

  // d_out doubles as scratch before the final FFN2 write:
  //   vT (8 MB bf16 [2048][2048]) + vmean (8 KB fp32) — both dead by then.
  unsigned short* vT    = (unsigned short*)d_out;
  float*          vmean = (float*)((char*)d_out + 8*MB);

  dim3 blk(256), blk512(512);
  transpose_cast<<<dim3(32,32),  blk, 0, stream>>>(wq, wqT, Dz, Dz);
  transpose_cast<<<dim3(32,32),  blk, 0, stream>>>(wk, wkT, Dz, Dz);
  transpose_cast<<<dim3(32,32),  blk, 0, stream>>>(wv, wvT, Dz, Dz);
  transpose_cast<<<dim3(32,32),  blk, 0, stream>>>(wo, woT, Dz, Dz);
  transpose_cast<<<dim3(128,32), blk, 0, stream>>>(w1, w1T, Dz, Fz);
  transpose_cast<<<dim3(32,128), blk, 0, stream>>>(w2, w2T, Fz, Dz);

  dim3 gln(ROWS);
  dim3 gqkv(3*Dz/256, ROWS/256);  // (12,16) fused QKV, 256^2 tiles
  dim3 gf1(Fz/256,  ROWS/256);    // (16,16) ffn1
  dim3 gn64(Dz/64,  ROWS/128);    // (16,32) = 512 blocks, 2/CU
  dim3 gattn(Sz/128, Hz, Bz);
  dim3 gvm(Hz, Bz);
  dim3 gvt(Sz/32, Bz*Hz*HDz/32);  // (64,64) V transpose

  // ---- block 1: h = attn(LN1(x)) + x ----
  ln_kernel<<<gln, blk, 0, stream>>>(x, ln1g, ln1b, lnb);
  gemm256<<<gqkv, blk512, 0, stream>>>(lnb, wqkvT, nullptr, nullptr, nullptr, q, ROWS, 3*Dz, Dz, Dz, Dz, 0, 1);
  transpose_bf<<<gvt, blk, 0, stream>>>(v, vT);
  vmean_kernel<<<gvm, blk, 0, stream>>>(v, vmean);
  attn_mfma<<<gattn, blk, 0, stream>>>(q, k, vT, vmean, ctx);
  gemm_n64<<<gn64, blk, 0, stream>>>(ctx, woT, bo, x, trunk, nullptr, ROWS, Dz, Dz);

  // ---- block 2: out = ffn(attn(LN2(h))) + h ----
  ln_kernel<<<gln, blk, 0, stream>>>(trunk, ln2g, ln2b, lnb);
  gemm256<<<gqkv, blk512, 0, stream>>>(lnb, wqkvT, nullptr, nullptr, nullptr, q, ROWS, 3*Dz, Dz, Dz, Dz, 0, 1);
  transpose_bf<<<gvt, blk, 0, stream>>>(v, vT);
  vmean_kernel<<<gvm, blk, 0, stream>>>(v, vmean);
  attn_mfma<<<gattn, blk, 0, stream>>>(q, k, vT, vmean, ctx);
  gemm_n64<<<gn64, blk, 0, stream>>>(ctx, woT, bo, nullptr, nullptr, lnb, ROWS, Dz, Dz);
  gemm256<<<gf1, blk512, 0, stream>>>(lnb, w1T, b1, nullptr, nullptr, mid, ROWS, Fz, Dz, Dz, Dz, 1, 0);
  if (splitk) {
    gemm256<<<dim3(4,16,4), blk512, 0, stream>>>(mid, w2T, nullptr, nullptr, part, nullptr, ROWS, Dz, Fz/4, Fz, Fz, 0, 0);
    reduce4<<<dim3(4096), blk, 0, stream>>>(part, b2, trunk, out);
  } else {
    gemm_n64<<<gn64, blk, 0, stream>>>(mid, w2T, b2, trunk, out, nullptr, ROWS, Dz, Fz);
  }
}

// Round 3
// 510.801 us; speedup vs baseline: 1.0574x; 1.0523x over previous
//
#include <hip/hip_runtime.h>
#include <hip/hip_bf16.h>
#include <math.h>

#define Bz 2
#define Sz 2048
#define Dz 1024
#define Hz 16
#define HDz 64
#define Fz 4096
#define ROWS (Bz*Sz)          // 4096
#define EPSf 1e-5f
#define NEGf -1e9f
#define SC2f 0.1803368801111204f   // 0.125 * log2(e)

typedef __attribute__((ext_vector_type(8))) short short8;   // 8 bf16 (4 VGPRs)
typedef __attribute__((ext_vector_type(4))) float floatx4;  // MFMA C/D

__device__ __forceinline__ unsigned short f2bf(float f){
  __hip_bfloat16 h = __float2bfloat16(f);
  return *(unsigned short*)&h;
}
__device__ __forceinline__ float bf2f(unsigned short u){
  union { unsigned x; float f; } a; a.x = ((unsigned)u) << 16; return a.f;
}

// exact-accuracy gelu via A&S 7.1.26 erf (|err|<=1.5e-7)
__device__ __forceinline__ float fast_gelu(float x){
  float t  = fabsf(x) * 0.70710678118654752f;
  float kk = __builtin_amdgcn_rcpf(1.0f + 0.3275911f * t);
  float poly = ((((1.061405429f*kk - 1.453152027f)*kk + 1.421413741f)*kk
                 - 0.284496736f)*kk + 0.254829592f)*kk;
  float er = 1.0f - poly * __expf(-t*t);
  er = copysignf(er, x);
  return 0.5f * x * (1.0f + er);
}

// async global->LDS, 16 B per lane, LDS dest = wave-uniform base + lane*16
__device__ __forceinline__ void gload16(const void* g, void* l){
  __builtin_amdgcn_global_load_lds(
      (const __attribute__((address_space(1))) unsigned int*)g,
      (__attribute__((address_space(3))) unsigned int*)l, 16, 0, 0);
}

// raw barrier (no implicit vmcnt(0) drain, unlike __syncthreads)
__device__ __forceinline__ void bar(){
  asm volatile("" ::: "memory");
  __builtin_amdgcn_s_barrier();
  asm volatile("" ::: "memory");
}
#define WAITV6 asm volatile("s_waitcnt vmcnt(6)" ::: "memory")
#define WAITV0 asm volatile("s_waitcnt vmcnt(0)" ::: "memory")
#define WL0    asm volatile("s_waitcnt lgkmcnt(0)" ::: "memory")

// XCD-clustered block remap (used by gemm_n64)
__device__ __forceinline__ void xcd_remap(int& bmblk, int& bnblk){
  int gx = gridDim.x, gy = gridDim.y;
  int id = blockIdx.y * gx + blockIdx.x;
  int xcd = id & 7, local = id >> 3;
  bnblk = local % gx;
  bmblk = xcd * (gy >> 3) + local / gx;
}

// ---------------- weight transpose + fp32->bf16 cast: W[K][N] -> Wt[N][K] ---
__global__ __launch_bounds__(256)
void transpose_cast(const float* __restrict__ W, unsigned short* __restrict__ Wt,
                    int K, int N)
{
  __shared__ unsigned short Ts[32][33];
  int n0 = blockIdx.x*32, k0 = blockIdx.y*32;
  int r = threadIdx.x >> 3, c0 = (threadIdx.x & 7) * 4;
  float4 w4 = *(const float4*)(W + (size_t)(k0+r)*N + n0 + c0);
  Ts[r][c0+0] = f2bf(w4.x); Ts[r][c0+1] = f2bf(w4.y);
  Ts[r][c0+2] = f2bf(w4.z); Ts[r][c0+3] = f2bf(w4.w);
  __syncthreads();
  unsigned v0 = Ts[c0+0][r], v1 = Ts[c0+1][r], v2 = Ts[c0+2][r], v3 = Ts[c0+3][r];
  uint2 p; p.x = v0 | (v1<<16); p.y = v2 | (v3<<16);
  *(uint2*)(Wt + (size_t)(n0+r)*K + k0 + c0) = p;
}

// ---------------- V transpose (bf16): v[b][s][h*64+d] -> vT[(b*16+h)*64+d][s]
__global__ __launch_bounds__(256)
void transpose_bf(const unsigned short* __restrict__ V, unsigned short* __restrict__ VT)
{
  __shared__ unsigned short Ts[32][33];
  int st = blockIdx.x*32;           // s-tile
  int R0 = blockIdx.y*32;           // output-row tile (R = (b*16+h)*64+d)
  int b = R0 >> 10, hd0 = R0 & 1023;
  int r = threadIdx.x >> 3, c0 = (threadIdx.x & 7) * 4;
  uint2 w = *(const uint2*)(V + (size_t)(b*Sz + st + r)*Dz + hd0 + c0);
  Ts[r][c0+0] = (unsigned short)(w.x & 0xffff);
  Ts[r][c0+1] = (unsigned short)(w.x >> 16);
  Ts[r][c0+2] = (unsigned short)(w.y & 0xffff);
  Ts[r][c0+3] = (unsigned short)(w.y >> 16);
  __syncthreads();
  unsigned v0 = Ts[c0+0][r], v1 = Ts[c0+1][r], v2 = Ts[c0+2][r], v3 = Ts[c0+3][r];
  uint2 p; p.x = v0 | (v1<<16); p.y = v2 | (v3<<16);
  *(uint2*)(VT + (size_t)(R0+r)*Sz + st + c0) = p;
}

// ---------------- LayerNorm: fp32 in -> bf16 out, one block per row --------
__global__ __launch_bounds__(256)
void ln_kernel(const float* __restrict__ in, const float* __restrict__ gam,
               const float* __restrict__ bet, unsigned short* __restrict__ out)
{
  int row = blockIdx.x, t = threadIdx.x;
  size_t base = (size_t)row * Dz;
  int c0 = t * 4;
  float4 x4 = *(const float4*)(in + base + c0);
  float v[4] = {x4.x, x4.y, x4.z, x4.w};
  float s = v[0]+v[1]+v[2]+v[3];
  #pragma unroll
  for (int off=32; off>0; off>>=1) s += __shfl_down(s, off, 64);
  __shared__ float ws[4];
  int lane = t & 63, wid = t >> 6;
  if (lane == 0) ws[wid] = s;
  __syncthreads();
  float mu = (ws[0]+ws[1]+ws[2]+ws[3]) * (1.0f/Dz);
  __syncthreads();
  float d0=v[0]-mu, d1=v[1]-mu, d2=v[2]-mu, d3=v[3]-mu;
  float s2 = d0*d0+d1*d1+d2*d2+d3*d3;
  #pragma unroll
  for (int off=32; off>0; off>>=1) s2 += __shfl_down(s2, off, 64);
  if (lane == 0) ws[wid] = s2;
  __syncthreads();
  float var = (ws[0]+ws[1]+ws[2]+ws[3]) * (1.0f/Dz);
  float rstd = rsqrtf(var + EPSf);
  float4 g4 = *(const float4*)(gam + c0);
  float4 b4 = *(const float4*)(bet + c0);
  unsigned r0 = f2bf((v[0]-mu)*rstd*g4.x + b4.x);
  unsigned r1 = f2bf((v[1]-mu)*rstd*g4.y + b4.y);
  unsigned r2 = f2bf((v[2]-mu)*rstd*g4.z + b4.z);
  unsigned r3 = f2bf((v[3]-mu)*rstd*g4.w + b4.w);
  uint2 p; p.x = r0 | (r1<<16); p.y = r2 | (r3<<16);
  *(uint2*)(out + base + c0) = p;
}

// ===========================================================================
// 256x256-tile, BK=64, 8-wave, 8-phase GEMM (HK-style schedule, plain HIP).
// (unchanged — verified)
// ===========================================================================
#define STG_A(buf, half, k0) { \
  _Pragma("unroll") for (int c_=0;c_<2;c_++){ \
    int sg_ = c_*8 + wave; \
    int row0_ = ((sg_>>3)<<7) + ((sg_&7)<<3) + ((half)<<6); \
    gload16(pA[half][c_] + (k0), &As[buf][row0_*64]); } }

#define STG_B(buf, jh, k0) { \
  _Pragma("unroll") for (int c_=0;c_<2;c_++){ \
    int sg_ = c_*8 + wave; int rho0_ = sg_<<3; \
    gload16(pB[jh][c_] + (k0), &Bs[buf][jh][rho0_*64]); } }

#define READ_A4(dst, buf, ihalf) { \
  _Pragma("unroll") for (int ii_=0; ii_<4; ++ii_){ \
    int row_ = wm*128 + ((ihalf)*4+ii_)*16 + l15; \
    _Pragma("unroll") for (int ks_=0; ks_<2; ++ks_){ \
      int slot_ = (ks_*4+quad) ^ (l15&7); \
      dst[ii_][ks_] = *(const short8*)&As[buf][row_*64 + slot_*8]; } } }

#define READ_B2(dst, buf, jh) { \
  _Pragma("unroll") for (int jl_=0; jl_<2; ++jl_){ \
    int rho_ = wn*32 + jl_*16 + l15; \
    _Pragma("unroll") for (int ks_=0; ks_<2; ++ks_){ \
      int slot_ = (ks_*4+quad) ^ (l15&7); \
      dst[jl_][ks_] = *(const short8*)&Bs[buf][jh][rho_*64 + slot_*8]; } } }

#define MFMA_PH(IH, JH, AF, BF) { \
  __builtin_amdgcn_s_setprio(1); \
  _Pragma("unroll") for (int ii_=0; ii_<4; ++ii_){ \
    _Pragma("unroll") for (int jl_=0; jl_<2; ++jl_){ \
      floatx4 c_ = acc[(IH)*4+ii_][(JH)*2+jl_]; \
      c_ = __builtin_amdgcn_mfma_f32_16x16x32_bf16(AF[ii_][0], BF[jl_][0], c_, 0,0,0); \
      c_ = __builtin_amdgcn_mfma_f32_16x16x32_bf16(AF[ii_][1], BF[jl_][1], c_, 0,0,0); \
      acc[(IH)*4+ii_][(JH)*2+jl_] = c_; } } \
  __builtin_amdgcn_s_setprio(0); }

__global__ __launch_bounds__(512, 2)
void gemm256(const unsigned short* __restrict__ A,
             const unsigned short* __restrict__ Bt,
             const float* __restrict__ bias, const float* __restrict__ res,
             float* __restrict__ outf, unsigned short* __restrict__ outb,
             int M, int N, int K, int lda, int ldb, int act, int qkvmode)
{
  __shared__ unsigned short As[2][256*64];     // [buf][row(256)][k(64)], swizzled slots
  __shared__ unsigned short Bs[2][2][128*64];  // [buf][jh][wn*32+jl*16+l15][k(64)]

  int t = threadIdx.x;
  int wave = t >> 6, lane = t & 63;
  int l15 = lane & 15, quad = lane >> 4;
  int wm = wave >> 2, wn = wave & 3;           // 2x4 wave grid, wave tile 128x64

  int nN = gridDim.x, nM = gridDim.y;
  int id = blockIdx.y * nN + blockIdx.x;
  int xcd = id & 7, local = id >> 3;
  int bnblk = local % nN;
  int bmblk = xcd * (nM >> 3) + local / nN;
  int bm = bmblk * 256, bn = bnblk * 256;

  if (gridDim.z > 1){
    A    += (size_t)blockIdx.z * K;
    Bt   += (size_t)blockIdx.z * K;
    outf += (size_t)blockIdx.z * ((size_t)M * N);
  }

  int lrow = lane >> 3;                         // 0..7 rows within a 1KB piece
  int lcol = ((lane & 7) ^ (lane >> 3)) * 8;    // inverse-swizzled source chunk

  const unsigned short* pA[2][2];
  const unsigned short* pB[2][2];
  #pragma unroll
  for (int half=0; half<2; half++)
    #pragma unroll
    for (int c=0;c<2;c++){
      int sg = c*8 + wave;
      int row0 = ((sg>>3)<<7) + ((sg&7)<<3) + (half<<6);
      pA[half][c] = A + (size_t)(bm + row0 + lrow)*lda + lcol;
    }
  #pragma unroll
  for (int jh=0; jh<2; jh++)
    #pragma unroll
    for (int c=0;c<2;c++){
      int sg = c*8 + wave;
      int rho0 = sg<<3;
      int gn = ((rho0>>5)<<6) + (jh<<5) + (rho0&31);
      pB[jh][c] = Bt + (size_t)(bn + gn + lrow)*ldb + lcol;
    }

  floatx4 acc[8][4];
  #pragma unroll
  for (int i=0;i<8;i++)
    #pragma unroll
    for (int j=0;j<4;j++) acc[i][j] = (floatx4){0.f,0.f,0.f,0.f};

  STG_A(0, 0, 0);  STG_A(0, 1, 0);
  STG_B(0, 0, 0);  STG_B(0, 1, 0);
  STG_A(1, 0, 64); STG_A(1, 1, 64);
  STG_B(1, 0, 64);
  WAITV6;
  bar();

  int NKT = K >> 6;
  int nIter = NKT >> 1;
  for (int it = 0; it < nIter; ++it){
    bool more = (it + 1 < nIter);
    int k0B  = (2*it+1) << 6;
    int k0A2 = (2*it+2) << 6;
    int k0B2 = (2*it+3) << 6;
    short8 aLo[4][2], aHi[4][2], bcur[2][2];

    READ_A4(aLo, 0, 0);
    READ_B2(bcur, 0, 0);
    STG_B(1, 1, k0B);
    bar(); WL0;
    MFMA_PH(0, 0, aLo, bcur);
    bar();

    READ_A4(aHi, 0, 1);
    READ_B2(bcur, 0, 0);
    if (more) STG_A(0, 0, k0A2);
    bar(); WL0;
    MFMA_PH(1, 0, aHi, bcur);
    bar();

    READ_B2(bcur, 0, 1);
    if (more) STG_A(0, 1, k0A2);
    bar(); WL0;
    MFMA_PH(0, 1, aLo, bcur);
    bar();

    if (more) { STG_B(0, 0, k0A2); WAITV6; }
    else      { WAITV0; }
    bar();
    MFMA_PH(1, 1, aHi, bcur);
    bar();

    READ_A4(aLo, 1, 0);
    READ_B2(bcur, 1, 0);
    if (more) STG_B(0, 1, k0A2);
    bar(); WL0;
    MFMA_PH(0, 0, aLo, bcur);
    bar();

    READ_A4(aHi, 1, 1);
    READ_B2(bcur, 1, 0);
    if (more) STG_A(1, 0, k0B2);
    bar(); WL0;
    MFMA_PH(1, 0, aHi, bcur);
    bar();

    READ_B2(bcur, 1, 1);
    if (more) STG_A(1, 1, k0B2);
    bar(); WL0;
    MFMA_PH(0, 1, aLo, bcur);
    bar();

    if (more) { STG_B(1, 0, k0B2); WAITV6; }
    bar();
    MFMA_PH(1, 1, aHi, bcur);
    bar();
  }

  float bj[4];
  #pragma unroll
  for (int j=0;j<4;j++) bj[j] = bias ? bias[bn + wn*64 + j*16 + l15] : 0.f;

  size_t selbase = 0; int ncol = N; int bnl = bn;
  if (qkvmode){ selbase = (size_t)(bn >> 10) * ((size_t)M * 1024); ncol = 1024; bnl = bn & 1023; }

  #pragma unroll
  for (int i=0;i<8;i++){
    int row0 = bm + wm*128 + i*16 + quad*4;
    #pragma unroll
    for (int r=0;r<4;r++){
      size_t rowoff = selbase + (size_t)(row0 + r) * ncol;
      #pragma unroll
      for (int j=0;j<4;j++){
        float v = acc[i][j][r] + bj[j];
        if (act) v = fast_gelu(v);
        size_t off = rowoff + bnl + wn*64 + j*16 + l15;
        if (res) v += res[off];
        if (outf) outf[off] = v;
        else      outb[off] = f2bf(v);
      }
    }
  }
}

// ---------------- MFMA GEMM 128x64, BK=64, double-buffered ------------------
__global__ __launch_bounds__(256)
void gemm_n64(const unsigned short* __restrict__ A,
              const unsigned short* __restrict__ Bt,
              const float* __restrict__ bias, const float* __restrict__ res,
              float* __restrict__ outf, unsigned short* __restrict__ outb,
              int M, int N, int K)
{
  __shared__ unsigned short As[2][128*64];   // [m][k], swizzled blocks
  __shared__ unsigned short Bs[2][64*64];    // [n][k]
  int t = threadIdx.x;
  int bmblk, bnblk; xcd_remap(bmblk, bnblk);
  int bm = bmblk * 128, bn = bnblk * 64;
  int wave = t >> 6, lane = t & 63;
  int l15 = lane & 15, quad = lane >> 4;
  int arow = lane >> 3;
  int acbg = ((lane & 7) ^ arow) * 8;
  const unsigned short* gA = A  + (size_t)(bm + wave*32 + arow)*K + acbg;
  const unsigned short* gB = Bt + (size_t)(bn + wave*16 + arow)*K + acbg;

  floatx4 acc[2][4];
  #pragma unroll
  for (int i=0;i<2;i++)
    #pragma unroll
    for (int j=0;j<4;j++) acc[i][j] = (floatx4){0.f,0.f,0.f,0.f};

  int swr = (l15 & 7);   // read-side XOR key

  { // prologue: tile 0 -> buffer 0
    unsigned short* lA = &As[0][wave*32*64];
    unsigned short* lB = &Bs[0][wave*16*64];
    gload16(gA,                 lA);
    gload16(gA + (size_t)8*K,   lA + 8*64);
    gload16(gA + (size_t)16*K,  lA + 16*64);
    gload16(gA + (size_t)24*K,  lA + 24*64);
    gload16(gB,                 lB);
    gload16(gB + (size_t)8*K,   lB + 8*64);
  }

  int nIter = K >> 6;
  for (int it = 0; it < nIter; ++it) {
    __syncthreads();
    int cur = it & 1;
    if (it + 1 < nIter) {
      int k1 = (it+1) << 6;
      unsigned short* lA = &As[cur^1][wave*32*64];
      unsigned short* lB = &Bs[cur^1][wave*16*64];
      gload16(gA + k1,                 lA);
      gload16(gA + k1 + (size_t)8*K,   lA + 8*64);
      gload16(gA + k1 + (size_t)16*K,  lA + 16*64);
      gload16(gA + k1 + (size_t)24*K,  lA + 24*64);
      gload16(gB + k1,                 lB);
      gload16(gB + k1 + (size_t)8*K,   lB + 8*64);
    }
    const unsigned short* Ac = As[cur];
    const unsigned short* Bc = Bs[cur];
    #pragma unroll
    for (int ks=0; ks<2; ++ks){
      short8 af[2], bf[4];
      #pragma unroll
      for (int i=0;i<2;i++)
        af[i] = *(const short8*)&Ac[(wave*32 + i*16 + l15)*64 + ((ks*4 + quad) ^ swr)*8];
      #pragma unroll
      for (int j=0;j<4;j++)
        bf[j] = *(const short8*)&Bc[(j*16 + l15)*64 + ((ks*4 + quad) ^ swr)*8];
      #pragma unroll
      for (int i=0;i<2;i++)
        #pragma unroll
        for (int j=0;j<4;j++)
          acc[i][j] = __builtin_amdgcn_mfma_f32_16x16x32_bf16(af[i], bf[j], acc[i][j], 0, 0, 0);
    }
  }

  float bj[4];
  #pragma unroll
  for (int j=0;j<4;j++) bj[j] = bias ? bias[bn + j*16 + l15] : 0.f;

  #pragma unroll
  for (int i=0;i<2;i++){
    int row0 = bm + wave*32 + i*16 + quad*4;
    #pragma unroll
    for (int r=0;r<4;r++){
      size_t rowoff = (size_t)(row0 + r) * N;
      #pragma unroll
      for (int j=0;j<4;j++){
        float v = acc[i][j][r] + bj[j];
        size_t off = rowoff + bn + j*16 + l15;
        if (res) v += res[off];
        if (outf) outf[off] = v;
        else      outb[off] = f2bf(v);
      }
    }
  }
}

// ---------------- split-K reduce: out = sum(part[0..3]) + bias + res --------
__global__ __launch_bounds__(256)
void reduce4(const float* __restrict__ part, const float* __restrict__ bias,
             const float* __restrict__ res, float* __restrict__ out)
{
  const size_t NN = (size_t)ROWS * Dz;
  size_t i = ((size_t)blockIdx.x * 256 + threadIdx.x) * 4;  // one block per row
  float4 a = *(const float4*)(part + i);
  float4 b = *(const float4*)(part + NN + i);
  float4 c = *(const float4*)(part + 2*NN + i);
  float4 d = *(const float4*)(part + 3*NN + i);
  float4 r = *(const float4*)(res + i);
  int col = threadIdx.x * 4;
  float4 g = *(const float4*)(bias + col);
  float4 o;
  o.x = a.x+b.x+c.x+d.x + g.x + r.x;
  o.y = a.y+b.y+c.y+d.y + g.y + r.y;
  o.z = a.z+b.z+c.z+d.z + g.z + r.z;
  o.w = a.w+b.w+c.w+d.w + g.w + r.w;
  *(float4*)(out + i) = o;
}

// ---------------- V column-mean per (b,h): for the all-masked row S-1 -------
__global__ __launch_bounds__(256)
void vmean_kernel(const unsigned short* __restrict__ v, float* __restrict__ vm)
{
  int h = blockIdx.x, b = blockIdx.y;
  int t = threadIdx.x, d = t & 63, seg = t >> 6;
  float s = 0.f;
  for (int i=0;i<512;i++){
    int srow = seg*512 + i;
    s += bf2f(v[((size_t)(b*Sz + srow))*Dz + h*HDz + d]);
  }
  __shared__ float red[4][64];
  red[seg][d] = s;
  __syncthreads();
  if (seg == 0){
    float tot = red[0][d]+red[1][d]+red[2][d]+red[3][d];
    vm[(b*Hz + h)*HDz + d] = tot * (1.0f/2048.0f);
  }
}

// ---------------- MFMA flash attention v3 ----------------------------------
// Changes vs v2: (a) 512 threads / 8 waves per block (16 q-rows per wave) ->
// 16 waves/CU instead of 8 at identical LDS + global traffic; (b) diagonal
// tile peeled: off-diagonal tiles skip the per-element mask cmp+sel;
// (c) exp via single fused-scale v_exp_f32 (0.125*log2e folded);
// (d) s_setprio around MFMA clusters (T5).
#define ATT_STAGE_KV() { \
    *(uint4*)&Ks[sr*64 + ((kc2  ) ^ ksw)*8] = pk0; \
    *(uint4*)&Ks[sr*64 + ((kc2+1) ^ ksw)*8] = pk1; \
    *(uint4*)&Vts[vd*128 + (((vk8  )&8) | (((vk8  )^vsw)&7))*8] = pv0; \
    *(uint4*)&Vts[vd*128 + (((vk8+1)&8) | (((vk8+1)^vsw)&7))*8] = pv1; }

#define ATT_PREFETCH(tile) { \
    size_t off0_ = ((size_t)(b*Sz + (tile)*128 + sr))*Dz + h*HDz + sc; \
    pk0 = *(const uint4*)(Kg + off0_); pk1 = *(const uint4*)(Kg + off0_ + 8); \
    int vo_ = (tile)*128 + vc*16; \
    pv0 = *(const uint4*)(vrow + vo_); pv1 = *(const uint4*)(vrow + vo_ + 8); }

#define ATT_COMPUTE(MASKED) { \
  _Pragma("unroll") \
  for (int hh=0; hh<2; ++hh){ \
    floatx4 acc_s[4]; \
    _Pragma("unroll") for (int j=0;j<4;j++) acc_s[j] = (floatx4){0.f,0.f,0.f,0.f}; \
    __builtin_amdgcn_s_setprio(1); \
    _Pragma("unroll") \
    for (int ks=0;ks<2;ks++){ \
      short8 bk[4]; \
      _Pragma("unroll") \
      for (int j=0;j<4;j++) \
        bk[j] = *(const short8*)&Ks[(hh*64 + j*16 + l15)*64 + (((ks*4+quad) ^ (l15&7)))*8]; \
      _Pragma("unroll") \
      for (int j=0;j<4;j++) \
        acc_s[j] = __builtin_amdgcn_mfma_f32_16x16x32_bf16(aq[ks], bk[j], acc_s[j], 0, 0, 0); \
    } \
    __builtin_amdgcn_s_setprio(0); \
    _Pragma("unroll") \
    for (int j=0;j<4;j++){ \
      _Pragma("unroll") \
      for (int r=0;r<4;r++){ \
        float s2 = acc_s[j][r] * SC2f; \
        if (MASKED){ int kloc = hh*64 + j*16 + l15; if (kloc <= qloc + r) s2 = NEGf; } \
        float p = __builtin_amdgcn_exp2f(fminf(s2, 115.41f)); \
        lacc[r] += p; \
        Ps[wave*16 + quad*4 + r][j*16 + l15] = f2bf(p); \
      } \
    } \
    __builtin_amdgcn_s_setprio(1); \
    _Pragma("unroll") \
    for (int ks=0;ks<2;ks++){ \
      short8 ap, bv[4]; \
      ap = *(const short8*)&Ps[wave*16 + l15][ks*32 + quad*8]; \
      _Pragma("unroll") \
      for (int j=0;j<4;j++) \
        bv[j] = *(const short8*)&Vts[(j*16 + l15)*128 + (hh*8 + ((ks*4+quad) ^ (l15&7)))*8]; \
      _Pragma("unroll") \
      for (int j=0;j<4;j++) \
        acc_o[j] = __builtin_amdgcn_mfma_f32_16x16x32_bf16(ap, bv[j], acc_o[j], 0, 0, 0); \
    } \
    __builtin_amdgcn_s_setprio(0); \
  } }

__global__ __launch_bounds__(512, 4)
void attn_mfma(const unsigned short* __restrict__ Qg,
               const unsigned short* __restrict__ Kg,
               const unsigned short* __restrict__ VTg,
               const float* __restrict__ vmean,
               unsigned short* __restrict__ Og)
{
  __shared__ unsigned short Ks[128*64];    // [key][d], XOR-swizzled 8-chunks
  __shared__ unsigned short Vts[64*128];   // [d][key], XOR-swizzled 8-chunks
  __shared__ unsigned short Ps[128][72];   // Q staging, then P (wave-private 16-row stripes)

  int t = threadIdx.x;
  int wave = t >> 6, lane = t & 63;
  int l15 = lane & 15, quad = lane >> 4;
  int b = blockIdx.z, h = blockIdx.y;
  int qt = b ? (15 - (int)blockIdx.x) : (int)blockIdx.x;   // load-balance pairing

  { // stage Q tile (128 x 64) into Ps
    int r = t >> 2, c = (t & 3) * 16;
    const unsigned short* qp = Qg + ((size_t)(b*Sz + qt*128 + r))*Dz + h*HDz + c;
    uint4 q0 = *(const uint4*)(qp);
    uint4 q1 = *(const uint4*)(qp + 8);
    *(uint4*)&Ps[r][c]     = q0;
    *(uint4*)&Ps[r][c + 8] = q1;
  }

  // K staging coords: row sr, col chunk pair kc2,kc2+1
  int sr = t >> 2, sc = (t & 3) * 16;
  int kc2 = (t & 3) * 2, ksw = sr & 7;
  // V^T staging coords: row vd, key-chunk pair vk8,vk8+1
  int vd = t >> 3, vc = t & 7, vsw = vd & 7;
  int vk8 = vc * 2;
  const unsigned short* vrow = VTg + ((size_t)((b*Hz + h)*64 + vd))*Sz;

  uint4 pk0, pk1, pv0, pv1;
  ATT_PREFETCH(qt);

  __syncthreads();
  short8 aq[2];
  aq[0] = *(const short8*)&Ps[wave*16 + l15][quad*8];
  aq[1] = *(const short8*)&Ps[wave*16 + l15][32 + quad*8];

  floatx4 acc_o[4];
  #pragma unroll
  for (int j=0;j<4;j++) acc_o[j] = (floatx4){0.f,0.f,0.f,0.f};
  float lacc[4] = {0.f, 0.f, 0.f, 0.f};

  int qloc = wave*16 + quad*4;   // q row within tile (plus r)

  // ---- diagonal tile (masked) ----
  ATT_STAGE_KV();
  __syncthreads();
  if (qt + 1 < Sz/128) ATT_PREFETCH(qt+1);
  ATT_COMPUTE(1);

  // ---- off-diagonal tiles (no mask: kj > qrow always) ----
  for (int jt2 = qt+1; jt2 < Sz/128; ++jt2){
    __syncthreads();
    ATT_STAGE_KV();
    __syncthreads();
    if (jt2 + 1 < Sz/128) ATT_PREFETCH(jt2+1);
    ATT_COMPUTE(0);
  }

  // ---- epilogue: reduce l across the 16 column-lanes, normalize, write ----
  #pragma unroll
  for (int r=0;r<4;r++){
    float l = lacc[r];
    l += __shfl_xor(l, 1, 64);
    l += __shfl_xor(l, 2, 64);
    l += __shfl_xor(l, 4, 64);
    l += __shfl_xor(l, 8, 64);
    int qrow = qt*128 + wave*16 + quad*4 + r;
    float inv = 1.0f / l;                 // row S-1: substituted below
    size_t rowoff = ((size_t)(b*Sz + qrow))*Dz + h*HDz;
    #pragma unroll
    for (int j=0;j<4;j++){
      float ov = acc_o[j][r] * inv;
      if (qrow == Sz-1) ov = vmean[(b*Hz + h)*HDz + j*16 + l15];
      Og[rowoff + j*16 + l15] = f2bf(ov);
    }
  }
}

// ---------------------------------------------------------------------------
extern "C" void kernel_launch(void* const* d_in, const int* in_sizes, int n_in,
                              void* d_out, int out_size, void* d_ws, size_t ws_size,
                              hipStream_t stream)
{
  const float* x    = (const float*)d_in[0];
  const float* wq   = (const float*)d_in[1];
  const float* wk   = (const float*)d_in[2];
  const float* wv   = (const float*)d_in[3];
  const float* wo   = (const float*)d_in[4];
  const float* bo   = (const float*)d_in[5];
  const float* ln1g = (const float*)d_in[6];
  const float* ln1b = (const float*)d_in[7];
  const float* ln2g = (const float*)d_in[8];
  const float* ln2b = (const float*)d_in[9];
  const float* w1   = (const float*)d_in[10];
  const float* b1   = (const float*)d_in[11];
  const float* w2   = (const float*)d_in[12];
  const float* b2   = (const float*)d_in[13];
  float* out = (float*)d_out;

  const size_t MB = 1024*1024;
  char* w = (char*)d_ws;
  float*          trunk = (float*)(w);                  //  0..16  fp32 residual
  unsigned short* lnb   = (unsigned short*)(w + 16*MB); // 16..24  bf16 LN/a2
  unsigned short* q     = (unsigned short*)(w + 24*MB); // q,k,v contiguous 8 MB regions
  unsigned short* k     = (unsigned short*)(w + 32*MB);
  unsigned short* v     = (unsigned short*)(w + 40*MB);
  unsigned short* ctx   = (unsigned short*)(w + 48*MB);
  unsigned short* wqkvT = (unsigned short*)(w + 56*MB); // wq/wk/wv T concat [3072][1024]
  unsigned short* wqT   = wqkvT;
  unsigned short* wkT   = (unsigned short*)(w + 58*MB);
  unsigned short* wvT   = (unsigned short*)(w + 60*MB);
  unsigned short* woT   = (unsigned short*)(w + 62*MB);
  unsigned short* w1T   = (unsigned short*)(w + 64*MB); // [F][D] 8 MB
  unsigned short* w2T   = (unsigned short*)(w + 72*MB); // [D][F] 8 MB
  unsigned short* mid   = (unsigned short*)(w + 24*MB); // overlap: q/k/v/ctx dead
  float*          part  = (float*)(w + 80*MB);          // 64 MB split-K partials
  bool splitk = ws_size >= (size_t)144*MB;

  // d_out doubles as scratch before the final FFN2 write:
  //   vT (8 MB bf16 [2048][2048]) + vmean (8 KB fp32) — both dead by then.
  unsigned short* vT    = (unsigned short*)d_out;
  float*          vmean = (float*)((char*)d_out + 8*MB);

  dim3 blk(256), blk512(512);
  transpose_cast<<<dim3(32,32),  blk, 0, stream>>>(wq, wqT, Dz, Dz);
  transpose_cast<<<dim3(32,32),  blk, 0, stream>>>(wk, wkT, Dz, Dz);
  transpose_cast<<<dim3(32,32),  blk, 0, stream>>>(wv, wvT, Dz, Dz);
  transpose_cast<<<dim3(32,32),  blk, 0, stream>>>(wo, woT, Dz, Dz);
  transpose_cast<<<dim3(128,32), blk, 0, stream>>>(w1, w1T, Dz, Fz);
  transpose_cast<<<dim3(32,128), blk, 0, stream>>>(w2, w2T, Fz, Dz);

  dim3 gln(ROWS);
  dim3 gqkv(3*Dz/256, ROWS/256);  // (12,16) fused QKV, 256^2 tiles
  dim3 gf1(Fz/256,  ROWS/256);    // (16,16) ffn1
  dim3 gn64(Dz/64,  ROWS/128);    // (16,32) = 512 blocks, 2/CU
  dim3 gattn(Sz/128, Hz, Bz);
  dim3 gvm(Hz, Bz);
  dim3 gvt(Sz/32, Bz*Hz*HDz/32);  // (64,64) V transpose

  // ---- block 1: h = attn(LN1(x)) + x ----
  ln_kernel<<<gln, blk, 0, stream>>>(x, ln1g, ln1b, lnb);
  gemm256<<<gqkv, blk512, 0, stream>>>(lnb, wqkvT, nullptr, nullptr, nullptr, q, ROWS, 3*Dz, Dz, Dz, Dz, 0, 1);
  transpose_bf<<<gvt, blk, 0, stream>>>(v, vT);
  vmean_kernel<<<gvm, blk, 0, stream>>>(v, vmean);
  attn_mfma<<<gattn, blk512, 0, stream>>>(q, k, vT, vmean, ctx);
  gemm_n64<<<gn64, blk, 0, stream>>>(ctx, woT, bo, x, trunk, nullptr, ROWS, Dz, Dz);

  // ---- block 2: out = ffn(attn(LN2(h))) + h ----
  ln_kernel<<<gln, blk, 0, stream>>>(trunk, ln2g, ln2b, lnb);
  gemm256<<<gqkv, blk512, 0, stream>>>(lnb, wqkvT, nullptr, nullptr, nullptr, q, ROWS, 3*Dz, Dz, Dz, Dz, 0, 1);
  transpose_bf<<<gvt, blk, 0, stream>>>(v, vT);
  vmean_kernel<<<gvm, blk, 0, stream>>>(v, vmean);
  attn_mfma<<<gattn, blk512, 0, stream>>>(q, k, vT, vmean, ctx);
  gemm_n64<<<gn64, blk, 0, stream>>>(ctx, woT, bo, nullptr, nullptr, lnb, ROWS, Dz, Dz);
  gemm256<<<gf1, blk512, 0, stream>>>(lnb, w1T, b1, nullptr, nullptr, mid, ROWS, Fz, Dz, Dz, Dz, 1, 0);
  if (splitk) {
    gemm256<<<dim3(4,16,4), blk512, 0, stream>>>(mid, w2T, nullptr, nullptr, part, nullptr, ROWS, Dz, Fz/4, Fz, Fz, 0, 0);
    reduce4<<<dim3(4096), blk, 0, stream>>>(part, b2, trunk, out);
  } else {
    gemm_n64<<<gn64, blk, 0, stream>>>(mid, w2T, b2, trunk, out, nullptr, ROWS, Dz, Fz);
  }
}

// Round 4
// 453.020 us; speedup vs baseline: 1.1923x; 1.1275x over previous
//
#include <hip/hip_runtime.h>
#include <hip/hip_bf16.h>
#include <math.h>

#define Bz 2
#define Sz 2048
#define Dz 1024
#define Hz 16
#define HDz 64
#define Fz 4096
#define ROWS (Bz*Sz)          // 4096
#define EPSf 1e-5f
#define NEGf -1e9f
#define SC2f 0.1803368801111204f   // 0.125 * log2(e)

typedef __attribute__((ext_vector_type(8))) short short8;   // 8 bf16 (4 VGPRs)
typedef __attribute__((ext_vector_type(4))) float floatx4;  // MFMA C/D

__device__ __forceinline__ unsigned short f2bf(float f){
  __hip_bfloat16 h = __float2bfloat16(f);
  return *(unsigned short*)&h;
}
__device__ __forceinline__ float bf2f(unsigned short u){
  union { unsigned x; float f; } a; a.x = ((unsigned)u) << 16; return a.f;
}

// exact-accuracy gelu via A&S 7.1.26 erf (|err|<=1.5e-7)
__device__ __forceinline__ float fast_gelu(float x){
  float t  = fabsf(x) * 0.70710678118654752f;
  float kk = __builtin_amdgcn_rcpf(1.0f + 0.3275911f * t);
  float poly = ((((1.061405429f*kk - 1.453152027f)*kk + 1.421413741f)*kk
                 - 0.284496736f)*kk + 0.254829592f)*kk;
  float er = 1.0f - poly * __expf(-t*t);
  er = copysignf(er, x);
  return 0.5f * x * (1.0f + er);
}

// async global->LDS, 16 B per lane, LDS dest = wave-uniform base + lane*16
__device__ __forceinline__ void gload16(const void* g, void* l){
  __builtin_amdgcn_global_load_lds(
      (const __attribute__((address_space(1))) unsigned int*)g,
      (__attribute__((address_space(3))) unsigned int*)l, 16, 0, 0);
}

// raw barrier (no implicit vmcnt(0) drain, unlike __syncthreads)
__device__ __forceinline__ void bar(){
  asm volatile("" ::: "memory");
  __builtin_amdgcn_s_barrier();
  asm volatile("" ::: "memory");
}
#define WAITV6 asm volatile("s_waitcnt vmcnt(6)" ::: "memory")
#define WAITV0 asm volatile("s_waitcnt vmcnt(0)" ::: "memory")
#define WL0    asm volatile("s_waitcnt lgkmcnt(0)" ::: "memory")

// XCD-clustered block remap (used by gemm_n64)
__device__ __forceinline__ void xcd_remap(int& bmblk, int& bnblk){
  int gx = gridDim.x, gy = gridDim.y;
  int id = blockIdx.y * gx + blockIdx.x;
  int xcd = id & 7, local = id >> 3;
  bnblk = local % gx;
  bmblk = xcd * (gy >> 3) + local / gx;
}

// ---------------- fused weight transposes: W[K][N] -> Wt[N][K], bf16 -------
// 4 square DxD matrices in one launch (z picks), and one launch for w1/w2.
__device__ __forceinline__ void tc_body(const float* __restrict__ W,
                                        unsigned short* __restrict__ Wt,
                                        int K, int N, int n0, int k0)
{
  __shared__ unsigned short Ts[32][33];
  int r = threadIdx.x >> 3, c0 = (threadIdx.x & 7) * 4;
  float4 w4 = *(const float4*)(W + (size_t)(k0+r)*N + n0 + c0);
  Ts[r][c0+0] = f2bf(w4.x); Ts[r][c0+1] = f2bf(w4.y);
  Ts[r][c0+2] = f2bf(w4.z); Ts[r][c0+3] = f2bf(w4.w);
  __syncthreads();
  unsigned v0 = Ts[c0+0][r], v1 = Ts[c0+1][r], v2 = Ts[c0+2][r], v3 = Ts[c0+3][r];
  uint2 p; p.x = v0 | (v1<<16); p.y = v2 | (v3<<16);
  *(uint2*)(Wt + (size_t)(n0+r)*K + k0 + c0) = p;
}

__global__ __launch_bounds__(256)
void transpose_qkvo(const float* __restrict__ w0, unsigned short* __restrict__ t0,
                    const float* __restrict__ w1, unsigned short* __restrict__ t1,
                    const float* __restrict__ w2, unsigned short* __restrict__ t2,
                    const float* __restrict__ w3, unsigned short* __restrict__ t3)
{
  int z = blockIdx.z;
  const float* W = z==0 ? w0 : z==1 ? w1 : z==2 ? w2 : w3;
  unsigned short* T = z==0 ? t0 : z==1 ? t1 : z==2 ? t2 : t3;
  tc_body(W, T, Dz, Dz, blockIdx.x*32, blockIdx.y*32);
}

__global__ __launch_bounds__(256)
void transpose_ffn(const float* __restrict__ w1, unsigned short* __restrict__ w1T,
                   const float* __restrict__ w2, unsigned short* __restrict__ w2T)
{
  int z = blockIdx.z;
  const float* W = z ? w2 : w1;
  unsigned short* T = z ? w2T : w1T;
  int K = z ? Fz : Dz, N = z ? Dz : Fz;
  int n0 = (z ? blockIdx.y : blockIdx.x) * 32;
  int k0 = (z ? blockIdx.x : blockIdx.y) * 32;
  tc_body(W, T, K, N, n0, k0);
}

// ---------------- V transpose (bf16) + row-sum (for vmean) ------------------
// v[b][s][h*64+d] -> vT[(b*16+h)*64+d][s]; also vsum[R] += sum_s V (atomic).
__global__ __launch_bounds__(256)
void transpose_bf(const unsigned short* __restrict__ V, unsigned short* __restrict__ VT,
                  float* __restrict__ vsum)
{
  __shared__ unsigned short Ts[32][33];
  int st = blockIdx.x*32;           // s-tile
  int R0 = blockIdx.y*32;           // output-row tile (R = (b*16+h)*64+d)
  int b = R0 >> 10, hd0 = R0 & 1023;
  int r = threadIdx.x >> 3, c0 = (threadIdx.x & 7) * 4;
  uint2 w = *(const uint2*)(V + (size_t)(b*Sz + st + r)*Dz + hd0 + c0);
  Ts[r][c0+0] = (unsigned short)(w.x & 0xffff);
  Ts[r][c0+1] = (unsigned short)(w.x >> 16);
  Ts[r][c0+2] = (unsigned short)(w.y & 0xffff);
  Ts[r][c0+3] = (unsigned short)(w.y >> 16);
  __syncthreads();
  unsigned v0 = Ts[c0+0][r], v1 = Ts[c0+1][r], v2 = Ts[c0+2][r], v3 = Ts[c0+3][r];
  uint2 p; p.x = v0 | (v1<<16); p.y = v2 | (v3<<16);
  *(uint2*)(VT + (size_t)(R0+r)*Sz + st + c0) = p;
  // row-sum of the 4 transposed elements this thread wrote (row R0+r)
  float s = bf2f((unsigned short)v0) + bf2f((unsigned short)v1)
          + bf2f((unsigned short)v2) + bf2f((unsigned short)v3);
  s += __shfl_down(s, 1, 8);
  s += __shfl_down(s, 2, 8);
  s += __shfl_down(s, 4, 8);
  if ((threadIdx.x & 7) == 0) atomicAdd(vsum + R0 + r, s);
}

// ---------------- LayerNorm: fp32 in -> bf16 out, one block per row --------
__global__ __launch_bounds__(256)
void ln_kernel(const float* __restrict__ in, const float* __restrict__ gam,
               const float* __restrict__ bet, unsigned short* __restrict__ out)
{
  int row = blockIdx.x, t = threadIdx.x;
  size_t base = (size_t)row * Dz;
  int c0 = t * 4;
  float4 x4 = *(const float4*)(in + base + c0);
  float v[4] = {x4.x, x4.y, x4.z, x4.w};
  float s = v[0]+v[1]+v[2]+v[3];
  #pragma unroll
  for (int off=32; off>0; off>>=1) s += __shfl_down(s, off, 64);
  __shared__ float ws[4];
  int lane = t & 63, wid = t >> 6;
  if (lane == 0) ws[wid] = s;
  __syncthreads();
  float mu = (ws[0]+ws[1]+ws[2]+ws[3]) * (1.0f/Dz);
  __syncthreads();
  float d0=v[0]-mu, d1=v[1]-mu, d2=v[2]-mu, d3=v[3]-mu;
  float s2 = d0*d0+d1*d1+d2*d2+d3*d3;
  #pragma unroll
  for (int off=32; off>0; off>>=1) s2 += __shfl_down(s2, off, 64);
  if (lane == 0) ws[wid] = s2;
  __syncthreads();
  float var = (ws[0]+ws[1]+ws[2]+ws[3]) * (1.0f/Dz);
  float rstd = rsqrtf(var + EPSf);
  float4 g4 = *(const float4*)(gam + c0);
  float4 b4 = *(const float4*)(bet + c0);
  unsigned r0 = f2bf((v[0]-mu)*rstd*g4.x + b4.x);
  unsigned r1 = f2bf((v[1]-mu)*rstd*g4.y + b4.y);
  unsigned r2 = f2bf((v[2]-mu)*rstd*g4.z + b4.z);
  unsigned r3 = f2bf((v[3]-mu)*rstd*g4.w + b4.w);
  uint2 p; p.x = r0 | (r1<<16); p.y = r2 | (r3<<16);
  *(uint2*)(out + base + c0) = p;
}

// ===========================================================================
// 256x256-tile, BK=64, 8-wave, 8-phase GEMM — single-barrier snake schedule.
// Per phase: reads(p); STG(p); lgkmcnt(0); [vmcnt@4/8]; s_barrier; MFMA(p).
// lgkmcnt BEFORE the barrier => at every rendezvous all ds_reads are complete,
// making the old second barrier unnecessary; MFMA(p)'s backlog then executes
// concurrently with reads(p+1) (LDS pipe || matrix pipe).
// Snake quadrant order (0,0)->(1,0)->(1,1)->(0,1): 48 ds_read_b128/iter
// (was 56), same register footprint (aLo held ph1-4, aHi ph2-3, b reused).
// Region schedule / vmcnt proofs:
//   ph1 STG buf1.Bjh1(2t+1)  ph2 STG buf0.A-h0(2t+2)  ph3 STG buf0.A-h1
//   ph4 STG buf0.Bjh0 +vmcnt(6): drains ph6',7',8',1 => buf1 complete pre-ph5
//   ph5 STG buf0.Bjh1        ph6 STG buf1.A-h0(2t+3)  ph7 STG buf1.A-h1
//   ph8 STG buf1.Bjh0 +vmcnt(6): drains ph2,3,4,5 => buf0(2t+2) complete
// WAR: each STG(p) region is disjoint from reads(p) (checked per phase); all
// older reads completed pre-barrier.
// ===========================================================================
#define STG_A(buf, half, k0) { \
  _Pragma("unroll") for (int c_=0;c_<2;c_++){ \
    int sg_ = c_*8 + wave; \
    int row0_ = ((sg_>>3)<<7) + ((sg_&7)<<3) + ((half)<<6); \
    gload16(pA[half][c_] + (k0), &As[buf][row0_*64]); } }

#define STG_B(buf, jh, k0) { \
  _Pragma("unroll") for (int c_=0;c_<2;c_++){ \
    int sg_ = c_*8 + wave; int rho0_ = sg_<<3; \
    gload16(pB[jh][c_] + (k0), &Bs[buf][jh][rho0_*64]); } }

#define READ_A4(dst, buf, ihalf) { \
  _Pragma("unroll") for (int ii_=0; ii_<4; ++ii_){ \
    int row_ = wm*128 + ((ihalf)*4+ii_)*16 + l15; \
    _Pragma("unroll") for (int ks_=0; ks_<2; ++ks_){ \
      int slot_ = (ks_*4+quad) ^ (l15&7); \
      dst[ii_][ks_] = *(const short8*)&As[buf][row_*64 + slot_*8]; } } }

#define READ_B2(dst, buf, jh) { \
  _Pragma("unroll") for (int jl_=0; jl_<2; ++jl_){ \
    int rho_ = wn*32 + jl_*16 + l15; \
    _Pragma("unroll") for (int ks_=0; ks_<2; ++ks_){ \
      int slot_ = (ks_*4+quad) ^ (l15&7); \
      dst[jl_][ks_] = *(const short8*)&Bs[buf][jh][rho_*64 + slot_*8]; } } }

#define MFMA_PH(IH, JH, AF, BF) { \
  __builtin_amdgcn_s_setprio(1); \
  _Pragma("unroll") for (int ii_=0; ii_<4; ++ii_){ \
    _Pragma("unroll") for (int jl_=0; jl_<2; ++jl_){ \
      floatx4 c_ = acc[(IH)*4+ii_][(JH)*2+jl_]; \
      c_ = __builtin_amdgcn_mfma_f32_16x16x32_bf16(AF[ii_][0], BF[jl_][0], c_, 0,0,0); \
      c_ = __builtin_amdgcn_mfma_f32_16x16x32_bf16(AF[ii_][1], BF[jl_][1], c_, 0,0,0); \
      acc[(IH)*4+ii_][(JH)*2+jl_] = c_; } } \
  __builtin_amdgcn_s_setprio(0); }

__global__ __launch_bounds__(512, 2)
void gemm256(const unsigned short* __restrict__ A,
             const unsigned short* __restrict__ Bt,
             const float* __restrict__ bias, const float* __restrict__ res,
             float* __restrict__ outf, unsigned short* __restrict__ outb,
             int M, int N, int K, int lda, int ldb, int act, int qkvmode)
{
  __shared__ unsigned short As[2][256*64];     // [buf][row(256)][k(64)], swizzled slots
  __shared__ unsigned short Bs[2][2][128*64];  // [buf][jh][wn*32+jl*16+l15][k(64)]

  int t = threadIdx.x;
  int wave = t >> 6, lane = t & 63;
  int l15 = lane & 15, quad = lane >> 4;
  int wm = wave >> 2, wn = wave & 3;           // 2x4 wave grid, wave tile 128x64

  int nN = gridDim.x, nM = gridDim.y;
  int id = blockIdx.y * nN + blockIdx.x;
  int xcd = id & 7, local = id >> 3;
  int bnblk = local % nN;
  int bmblk = xcd * (nM >> 3) + local / nN;
  int bm = bmblk * 256, bn = bnblk * 256;

  if (gridDim.z > 1){
    A    += (size_t)blockIdx.z * K;
    Bt   += (size_t)blockIdx.z * K;
    outf += (size_t)blockIdx.z * ((size_t)M * N);
  }

  int lrow = lane >> 3;                         // 0..7 rows within a 1KB piece
  int lcol = ((lane & 7) ^ (lane >> 3)) * 8;    // inverse-swizzled source chunk

  const unsigned short* pA[2][2];
  const unsigned short* pB[2][2];
  #pragma unroll
  for (int half=0; half<2; half++)
    #pragma unroll
    for (int c=0;c<2;c++){
      int sg = c*8 + wave;
      int row0 = ((sg>>3)<<7) + ((sg&7)<<3) + (half<<6);
      pA[half][c] = A + (size_t)(bm + row0 + lrow)*lda + lcol;
    }
  #pragma unroll
  for (int jh=0; jh<2; jh++)
    #pragma unroll
    for (int c=0;c<2;c++){
      int sg = c*8 + wave;
      int rho0 = sg<<3;
      int gn = ((rho0>>5)<<6) + (jh<<5) + (rho0&31);
      pB[jh][c] = Bt + (size_t)(bn + gn + lrow)*ldb + lcol;
    }

  floatx4 acc[8][4];
  #pragma unroll
  for (int i=0;i<8;i++)
    #pragma unroll
    for (int j=0;j<4;j++) acc[i][j] = (floatx4){0.f,0.f,0.f,0.f};

  // prologue: buf0 <- tile0 (4 regions), buf1 <- tile1 (A both halves, B-jh0)
  STG_A(0, 0, 0);  STG_A(0, 1, 0);
  STG_B(0, 0, 0);  STG_B(0, 1, 0);
  STG_A(1, 0, 64); STG_A(1, 1, 64);
  STG_B(1, 0, 64);
  WAITV6;                      // buf0's 8 loads landed
  bar();

  int NKT = K >> 6;
  int nIter = NKT >> 1;
  for (int it = 0; it < nIter; ++it){
    bool more = (it + 1 < nIter);
    int k0B  = (2*it+1) << 6;
    int k0A2 = (2*it+2) << 6;
    int k0B2 = (2*it+3) << 6;
    short8 aLo[4][2], aHi[4][2], bcur[2][2];

    // ---- ph1: buf0 (Lo, j0) ----
    READ_A4(aLo, 0, 0);
    READ_B2(bcur, 0, 0);
    STG_B(1, 1, k0B);
    WL0; bar();
    MFMA_PH(0, 0, aLo, bcur);

    // ---- ph2: buf0 (Hi, j0), b held ----
    READ_A4(aHi, 0, 1);
    if (more) STG_A(0, 0, k0A2);
    WL0; bar();
    MFMA_PH(1, 0, aHi, bcur);

    // ---- ph3: buf0 (Hi, j1), a held ----
    READ_B2(bcur, 0, 1);
    if (more) STG_A(0, 1, k0A2);
    WL0; bar();
    MFMA_PH(1, 1, aHi, bcur);

    // ---- ph4: buf0 (Lo, j1), both held ----
    if (more) { STG_B(0, 0, k0A2); WAITV6; }
    else      { WAITV0; }
    bar();
    MFMA_PH(0, 1, aLo, bcur);

    // ---- ph5: buf1 (Lo, j0) ----
    READ_A4(aLo, 1, 0);
    READ_B2(bcur, 1, 0);
    if (more) STG_B(0, 1, k0A2);
    WL0; bar();
    MFMA_PH(0, 0, aLo, bcur);

    // ---- ph6: buf1 (Hi, j0) ----
    READ_A4(aHi, 1, 1);
    if (more) STG_A(1, 0, k0B2);
    WL0; bar();
    MFMA_PH(1, 0, aHi, bcur);

    // ---- ph7: buf1 (Hi, j1) ----
    READ_B2(bcur, 1, 1);
    if (more) STG_A(1, 1, k0B2);
    WL0; bar();
    MFMA_PH(1, 1, aHi, bcur);

    // ---- ph8: buf1 (Lo, j1) ----
    if (more) { STG_B(1, 0, k0B2); WAITV6; }
    bar();
    MFMA_PH(0, 1, aLo, bcur);
  }

  float bj[4];
  #pragma unroll
  for (int j=0;j<4;j++) bj[j] = bias ? bias[bn + wn*64 + j*16 + l15] : 0.f;

  size_t selbase = 0; int ncol = N; int bnl = bn;
  if (qkvmode){ selbase = (size_t)(bn >> 10) * ((size_t)M * 1024); ncol = 1024; bnl = bn & 1023; }

  #pragma unroll
  for (int i=0;i<8;i++){
    int row0 = bm + wm*128 + i*16 + quad*4;
    #pragma unroll
    for (int r=0;r<4;r++){
      size_t rowoff = selbase + (size_t)(row0 + r) * ncol;
      #pragma unroll
      for (int j=0;j<4;j++){
        float v = acc[i][j][r] + bj[j];
        if (act) v = fast_gelu(v);
        size_t off = rowoff + bnl + wn*64 + j*16 + l15;
        if (res) v += res[off];
        if (outf) outf[off] = v;
        else      outb[off] = f2bf(v);
      }
    }
  }
}

// ---------------- MFMA GEMM 128x64, BK=64, double-buffered ------------------
__global__ __launch_bounds__(256)
void gemm_n64(const unsigned short* __restrict__ A,
              const unsigned short* __restrict__ Bt,
              const float* __restrict__ bias, const float* __restrict__ res,
              float* __restrict__ outf, unsigned short* __restrict__ outb,
              int M, int N, int K)
{
  __shared__ unsigned short As[2][128*64];   // [m][k], swizzled blocks
  __shared__ unsigned short Bs[2][64*64];    // [n][k]
  int t = threadIdx.x;
  int bmblk, bnblk; xcd_remap(bmblk, bnblk);
  int bm = bmblk * 128, bn = bnblk * 64;
  int wave = t >> 6, lane = t & 63;
  int l15 = lane & 15, quad = lane >> 4;
  int arow = lane >> 3;
  int acbg = ((lane & 7) ^ arow) * 8;
  const unsigned short* gA = A  + (size_t)(bm + wave*32 + arow)*K + acbg;
  const unsigned short* gB = Bt + (size_t)(bn + wave*16 + arow)*K + acbg;

  floatx4 acc[2][4];
  #pragma unroll
  for (int i=0;i<2;i++)
    #pragma unroll
    for (int j=0;j<4;j++) acc[i][j] = (floatx4){0.f,0.f,0.f,0.f};

  int swr = (l15 & 7);   // read-side XOR key

  { // prologue: tile 0 -> buffer 0
    unsigned short* lA = &As[0][wave*32*64];
    unsigned short* lB = &Bs[0][wave*16*64];
    gload16(gA,                 lA);
    gload16(gA + (size_t)8*K,   lA + 8*64);
    gload16(gA + (size_t)16*K,  lA + 16*64);
    gload16(gA + (size_t)24*K,  lA + 24*64);
    gload16(gB,                 lB);
    gload16(gB + (size_t)8*K,   lB + 8*64);
  }

  int nIter = K >> 6;
  for (int it = 0; it < nIter; ++it) {
    __syncthreads();
    int cur = it & 1;
    if (it + 1 < nIter) {
      int k1 = (it+1) << 6;
      unsigned short* lA = &As[cur^1][wave*32*64];
      unsigned short* lB = &Bs[cur^1][wave*16*64];
      gload16(gA + k1,                 lA);
      gload16(gA + k1 + (size_t)8*K,   lA + 8*64);
      gload16(gA + k1 + (size_t)16*K,  lA + 16*64);
      gload16(gA + k1 + (size_t)24*K,  lA + 24*64);
      gload16(gB + k1,                 lB);
      gload16(gB + k1 + (size_t)8*K,   lB + 8*64);
    }
    const unsigned short* Ac = As[cur];
    const unsigned short* Bc = Bs[cur];
    #pragma unroll
    for (int ks=0; ks<2; ++ks){
      short8 af[2], bf[4];
      #pragma unroll
      for (int i=0;i<2;i++)
        af[i] = *(const short8*)&Ac[(wave*32 + i*16 + l15)*64 + ((ks*4 + quad) ^ swr)*8];
      #pragma unroll
      for (int j=0;j<4;j++)
        bf[j] = *(const short8*)&Bc[(j*16 + l15)*64 + ((ks*4 + quad) ^ swr)*8];
      #pragma unroll
      for (int i=0;i<2;i++)
        #pragma unroll
        for (int j=0;j<4;j++)
          acc[i][j] = __builtin_amdgcn_mfma_f32_16x16x32_bf16(af[i], bf[j], acc[i][j], 0, 0, 0);
    }
  }

  float bj[4];
  #pragma unroll
  for (int j=0;j<4;j++) bj[j] = bias ? bias[bn + j*16 + l15] : 0.f;

  #pragma unroll
  for (int i=0;i<2;i++){
    int row0 = bm + wave*32 + i*16 + quad*4;
    #pragma unroll
    for (int r=0;r<4;r++){
      size_t rowoff = (size_t)(row0 + r) * N;
      #pragma unroll
      for (int j=0;j<4;j++){
        float v = acc[i][j][r] + bj[j];
        size_t off = rowoff + bn + j*16 + l15;
        if (res) v += res[off];
        if (outf) outf[off] = v;
        else      outb[off] = f2bf(v);
      }
    }
  }
}

// ---------------- split-K reduce: out = sum(part[0..3]) + bias + res --------
__global__ __launch_bounds__(256)
void reduce4(const float* __restrict__ part, const float* __restrict__ bias,
             const float* __restrict__ res, float* __restrict__ out)
{
  const size_t NN = (size_t)ROWS * Dz;
  size_t i = ((size_t)blockIdx.x * 256 + threadIdx.x) * 4;  // one block per row
  float4 a = *(const float4*)(part + i);
  float4 b = *(const float4*)(part + NN + i);
  float4 c = *(const float4*)(part + 2*NN + i);
  float4 d = *(const float4*)(part + 3*NN + i);
  float4 r = *(const float4*)(res + i);
  int col = threadIdx.x * 4;
  float4 g = *(const float4*)(bias + col);
  float4 o;
  o.x = a.x+b.x+c.x+d.x + g.x + r.x;
  o.y = a.y+b.y+c.y+d.y + g.y + r.y;
  o.z = a.z+b.z+c.z+d.z + g.z + r.z;
  o.w = a.w+b.w+c.w+d.w + g.w + r.w;
  *(float4*)(out + i) = o;
}

// ---------------- MFMA flash attention (v3, verified) -----------------------
#define ATT_STAGE_KV() { \
    *(uint4*)&Ks[sr*64 + ((kc2  ) ^ ksw)*8] = pk0; \
    *(uint4*)&Ks[sr*64 + ((kc2+1) ^ ksw)*8] = pk1; \
    *(uint4*)&Vts[vd*128 + (((vk8  )&8) | (((vk8  )^vsw)&7))*8] = pv0; \
    *(uint4*)&Vts[vd*128 + (((vk8+1)&8) | (((vk8+1)^vsw)&7))*8] = pv1; }

#define ATT_PREFETCH(tile) { \
    size_t off0_ = ((size_t)(b*Sz + (tile)*128 + sr))*Dz + h*HDz + sc; \
    pk0 = *(const uint4*)(Kg + off0_); pk1 = *(const uint4*)(Kg + off0_ + 8); \
    int vo_ = (tile)*128 + vc*16; \
    pv0 = *(const uint4*)(vrow + vo_); pv1 = *(const uint4*)(vrow + vo_ + 8); }

#define ATT_COMPUTE(MASKED) { \
  _Pragma("unroll") \
  for (int hh=0; hh<2; ++hh){ \
    floatx4 acc_s[4]; \
    _Pragma("unroll") for (int j=0;j<4;j++) acc_s[j] = (floatx4){0.f,0.f,0.f,0.f}; \
    __builtin_amdgcn_s_setprio(1); \
    _Pragma("unroll") \
    for (int ks=0;ks<2;ks++){ \
      short8 bk[4]; \
      _Pragma("unroll") \
      for (int j=0;j<4;j++) \
        bk[j] = *(const short8*)&Ks[(hh*64 + j*16 + l15)*64 + (((ks*4+quad) ^ (l15&7)))*8]; \
      _Pragma("unroll") \
      for (int j=0;j<4;j++) \
        acc_s[j] = __builtin_amdgcn_mfma_f32_16x16x32_bf16(aq[ks], bk[j], acc_s[j], 0, 0, 0); \
    } \
    __builtin_amdgcn_s_setprio(0); \
    _Pragma("unroll") \
    for (int j=0;j<4;j++){ \
      _Pragma("unroll") \
      for (int r=0;r<4;r++){ \
        float s2 = acc_s[j][r] * SC2f; \
        if (MASKED){ int kloc = hh*64 + j*16 + l15; if (kloc <= qloc + r) s2 = NEGf; } \
        float p = __builtin_amdgcn_exp2f(fminf(s2, 115.41f)); \
        lacc[r] += p; \
        Ps[wave*16 + quad*4 + r][j*16 + l15] = f2bf(p); \
      } \
    } \
    __builtin_amdgcn_s_setprio(1); \
    _Pragma("unroll") \
    for (int ks=0;ks<2;ks++){ \
      short8 ap, bv[4]; \
      ap = *(const short8*)&Ps[wave*16 + l15][ks*32 + quad*8]; \
      _Pragma("unroll") \
      for (int j=0;j<4;j++) \
        bv[j] = *(const short8*)&Vts[(j*16 + l15)*128 + (hh*8 + ((ks*4+quad) ^ (l15&7)))*8]; \
      _Pragma("unroll") \
      for (int j=0;j<4;j++) \
        acc_o[j] = __builtin_amdgcn_mfma_f32_16x16x32_bf16(ap, bv[j], acc_o[j], 0, 0, 0); \
    } \
    __builtin_amdgcn_s_setprio(0); \
  } }

__global__ __launch_bounds__(512, 4)
void attn_mfma(const unsigned short* __restrict__ Qg,
               const unsigned short* __restrict__ Kg,
               const unsigned short* __restrict__ VTg,
               const float* __restrict__ vmean,
               unsigned short* __restrict__ Og)
{
  __shared__ unsigned short Ks[128*64];    // [key][d], XOR-swizzled 8-chunks
  __shared__ unsigned short Vts[64*128];   // [d][key], XOR-swizzled 8-chunks
  __shared__ unsigned short Ps[128][72];   // Q staging, then P (wave-private 16-row stripes)

  int t = threadIdx.x;
  int wave = t >> 6, lane = t & 63;
  int l15 = lane & 15, quad = lane >> 4;
  int b = blockIdx.z, h = blockIdx.y;
  int qt = b ? (15 - (int)blockIdx.x) : (int)blockIdx.x;   // load-balance pairing

  { // stage Q tile (128 x 64) into Ps
    int r = t >> 2, c = (t & 3) * 16;
    const unsigned short* qp = Qg + ((size_t)(b*Sz + qt*128 + r))*Dz + h*HDz + c;
    uint4 q0 = *(const uint4*)(qp);
    uint4 q1 = *(const uint4*)(qp + 8);
    *(uint4*)&Ps[r][c]     = q0;
    *(uint4*)&Ps[r][c + 8] = q1;
  }

  // K staging coords: row sr, col chunk pair kc2,kc2+1
  int sr = t >> 2, sc = (t & 3) * 16;
  int kc2 = (t & 3) * 2, ksw = sr & 7;
  // V^T staging coords: row vd, key-chunk pair vk8,vk8+1
  int vd = t >> 3, vc = t & 7, vsw = vd & 7;
  int vk8 = vc * 2;
  const unsigned short* vrow = VTg + ((size_t)((b*Hz + h)*64 + vd))*Sz;

  uint4 pk0, pk1, pv0, pv1;
  ATT_PREFETCH(qt);

  __syncthreads();
  short8 aq[2];
  aq[0] = *(const short8*)&Ps[wave*16 + l15][quad*8];
  aq[1] = *(const short8*)&Ps[wave*16 + l15][32 + quad*8];

  floatx4 acc_o[4];
  #pragma unroll
  for (int j=0;j<4;j++) acc_o[j] = (floatx4){0.f,0.f,0.f,0.f};
  float lacc[4] = {0.f, 0.f, 0.f, 0.f};

  int qloc = wave*16 + quad*4;   // q row within tile (plus r)

  // ---- diagonal tile (masked) ----
  ATT_STAGE_KV();
  __syncthreads();
  if (qt + 1 < Sz/128) ATT_PREFETCH(qt+1);
  ATT_COMPUTE(1);

  // ---- off-diagonal tiles (no mask: kj > qrow always) ----
  for (int jt2 = qt+1; jt2 < Sz/128; ++jt2){
    __syncthreads();
    ATT_STAGE_KV();
    __syncthreads();
    if (jt2 + 1 < Sz/128) ATT_PREFETCH(jt2+1);
    ATT_COMPUTE(0);
  }

  // ---- epilogue: reduce l across the 16 column-lanes, normalize, write ----
  #pragma unroll
  for (int r=0;r<4;r++){
    float l = lacc[r];
    l += __shfl_xor(l, 1, 64);
    l += __shfl_xor(l, 2, 64);
    l += __shfl_xor(l, 4, 64);
    l += __shfl_xor(l, 8, 64);
    int qrow = qt*128 + wave*16 + quad*4 + r;
    float inv = 1.0f / l;                 // row S-1: substituted below
    size_t rowoff = ((size_t)(b*Sz + qrow))*Dz + h*HDz;
    #pragma unroll
    for (int j=0;j<4;j++){
      float ov = acc_o[j][r] * inv;
      if (qrow == Sz-1) ov = vmean[(b*Hz + h)*HDz + j*16 + l15] * (1.0f/2048.0f);
      Og[rowoff + j*16 + l15] = f2bf(ov);
    }
  }
}

// ---------------------------------------------------------------------------
extern "C" void kernel_launch(void* const* d_in, const int* in_sizes, int n_in,
                              void* d_out, int out_size, void* d_ws, size_t ws_size,
                              hipStream_t stream)
{
  const float* x    = (const float*)d_in[0];
  const float* wq   = (const float*)d_in[1];
  const float* wk   = (const float*)d_in[2];
  const float* wv   = (const float*)d_in[3];
  const float* wo   = (const float*)d_in[4];
  const float* bo   = (const float*)d_in[5];
  const float* ln1g = (const float*)d_in[6];
  const float* ln1b = (const float*)d_in[7];
  const float* ln2g = (const float*)d_in[8];
  const float* ln2b = (const float*)d_in[9];
  const float* w1   = (const float*)d_in[10];
  const float* b1   = (const float*)d_in[11];
  const float* w2   = (const float*)d_in[12];
  const float* b2   = (const float*)d_in[13];
  float* out = (float*)d_out;

  const size_t MB = 1024*1024;
  char* w = (char*)d_ws;
  float*          trunk = (float*)(w);                  //  0..16  fp32 residual
  unsigned short* lnb   = (unsigned short*)(w + 16*MB); // 16..24  bf16 LN/a2
  unsigned short* q     = (unsigned short*)(w + 24*MB); // q,k,v contiguous 8 MB regions
  unsigned short* k     = (unsigned short*)(w + 32*MB);
  unsigned short* v     = (unsigned short*)(w + 40*MB);
  unsigned short* ctx   = (unsigned short*)(w + 48*MB);
  unsigned short* wqkvT = (unsigned short*)(w + 56*MB); // wq/wk/wv T concat [3072][1024]
  unsigned short* wqT   = wqkvT;
  unsigned short* wkT   = (unsigned short*)(w + 58*MB);
  unsigned short* wvT   = (unsigned short*)(w + 60*MB);
  unsigned short* woT   = (unsigned short*)(w + 62*MB);
  unsigned short* w1T   = (unsigned short*)(w + 64*MB); // [F][D] 8 MB
  unsigned short* w2T   = (unsigned short*)(w + 72*MB); // [D][F] 8 MB
  unsigned short* mid   = (unsigned short*)(w + 24*MB); // overlap: q/k/v/ctx dead
  float*          part  = (float*)(w + 80*MB);          // 64 MB split-K partials
  bool splitk = ws_size >= (size_t)144*MB;

  // d_out doubles as scratch before the final FFN2 write:
  //   vT (8 MB bf16 [2048][2048]) + vmean sums (8 KB fp32) — both dead by then.
  unsigned short* vT    = (unsigned short*)d_out;
  float*          vmean = (float*)((char*)d_out + 8*MB);

  dim3 blk(256), blk512(512);
  transpose_qkvo<<<dim3(32,32,4), blk, 0, stream>>>(wq, wqT, wk, wkT, wv, wvT, wo, woT);
  transpose_ffn<<<dim3(128,32,2), blk, 0, stream>>>(w1, w1T, w2, w2T);

  dim3 gln(ROWS);
  dim3 gqkv(3*Dz/256, ROWS/256);  // (12,16) fused QKV, 256^2 tiles
  dim3 gf1(Fz/256,  ROWS/256);    // (16,16) ffn1
  dim3 gn64(Dz/64,  ROWS/128);    // (16,32) = 512 blocks, 2/CU
  dim3 gattn(Sz/128, Hz, Bz);
  dim3 gvt(Sz/32, Bz*Hz*HDz/32);  // (64,64) V transpose

  // ---- block 1: h = attn(LN1(x)) + x ----
  ln_kernel<<<gln, blk, 0, stream>>>(x, ln1g, ln1b, lnb);
  gemm256<<<gqkv, blk512, 0, stream>>>(lnb, wqkvT, nullptr, nullptr, nullptr, q, ROWS, 3*Dz, Dz, Dz, Dz, 0, 1);
  hipMemsetAsync(vmean, 0, 2048*sizeof(float), stream);
  transpose_bf<<<gvt, blk, 0, stream>>>(v, vT, vmean);
  attn_mfma<<<gattn, blk512, 0, stream>>>(q, k, vT, vmean, ctx);
  gemm_n64<<<gn64, blk, 0, stream>>>(ctx, woT, bo, x, trunk, nullptr, ROWS, Dz, Dz);

  // ---- block 2: out = ffn(attn(LN2(h))) + h ----
  ln_kernel<<<gln, blk, 0, stream>>>(trunk, ln2g, ln2b, lnb);
  gemm256<<<gqkv, blk512, 0, stream>>>(lnb, wqkvT, nullptr, nullptr, nullptr, q, ROWS, 3*Dz, Dz, Dz, Dz, 0, 1);
  hipMemsetAsync(vmean, 0, 2048*sizeof(float), stream);
  transpose_bf<<<gvt, blk, 0, stream>>>(v, vT, vmean);
  attn_mfma<<<gattn, blk512, 0, stream>>>(q, k, vT, vmean, ctx);
  gemm_n64<<<gn64, blk, 0, stream>>>(ctx, woT, bo, nullptr, nullptr, lnb, ROWS, Dz, Dz);
  gemm256<<<gf1, blk512, 0, stream>>>(lnb, w1T, b1, nullptr, nullptr, mid, ROWS, Fz, Dz, Dz, Dz, 1, 0);
  if (splitk) {
    gemm256<<<dim3(4,16,4), blk512, 0, stream>>>(mid, w2T, nullptr, nullptr, part, nullptr, ROWS, Dz, Fz/4, Fz, Fz, 0, 0);
    reduce4<<<dim3(4096), blk, 0, stream>>>(part, b2, trunk, out);
  } else {
    gemm_n64<<<gn64, blk, 0, stream>>>(mid, w2T, b2, trunk, out, nullptr, ROWS, Dz, Fz);
  }
}

// Round 5
// 439.852 us; speedup vs baseline: 1.2280x; 1.0299x over previous
//
#include <hip/hip_runtime.h>
#include <hip/hip_bf16.h>
#include <math.h>

#define Bz 2
#define Sz 2048
#define Dz 1024
#define Hz 16
#define HDz 64
#define Fz 4096
#define ROWS (Bz*Sz)          // 4096
#define EPSf 1e-5f
#define NEGf -1e9f
#define SC2f 0.1803368801111204f   // 0.125 * log2(e)

typedef __attribute__((ext_vector_type(8))) short short8;   // 8 bf16 (4 VGPRs)
typedef __attribute__((ext_vector_type(4))) float floatx4;  // MFMA C/D

__device__ __forceinline__ unsigned short f2bf(float f){
  __hip_bfloat16 h = __float2bfloat16(f);
  return *(unsigned short*)&h;
}
__device__ __forceinline__ float bf2f(unsigned short u){
  union { unsigned x; float f; } a; a.x = ((unsigned)u) << 16; return a.f;
}

// exact-accuracy gelu via A&S 7.1.26 erf (|err|<=1.5e-7)
__device__ __forceinline__ float fast_gelu(float x){
  float t  = fabsf(x) * 0.70710678118654752f;
  float kk = __builtin_amdgcn_rcpf(1.0f + 0.3275911f * t);
  float poly = ((((1.061405429f*kk - 1.453152027f)*kk + 1.421413741f)*kk
                 - 0.284496736f)*kk + 0.254829592f)*kk;
  float er = 1.0f - poly * __expf(-t*t);
  er = copysignf(er, x);
  return 0.5f * x * (1.0f + er);
}

// async global->LDS, 16 B per lane, LDS dest = wave-uniform base + lane*16
__device__ __forceinline__ void gload16(const void* g, void* l){
  __builtin_amdgcn_global_load_lds(
      (const __attribute__((address_space(1))) unsigned int*)g,
      (__attribute__((address_space(3))) unsigned int*)l, 16, 0, 0);
}

// raw barrier (no implicit vmcnt(0) drain, unlike __syncthreads)
__device__ __forceinline__ void bar(){
  asm volatile("" ::: "memory");
  __builtin_amdgcn_s_barrier();
  asm volatile("" ::: "memory");
}
#define WAITV4 asm volatile("s_waitcnt vmcnt(4)" ::: "memory")
#define WAITV0 asm volatile("s_waitcnt vmcnt(0)" ::: "memory")
#define WL0    asm volatile("s_waitcnt lgkmcnt(0)" ::: "memory")

// XCD-clustered block remap (used by gemm_n64)
__device__ __forceinline__ void xcd_remap(int& bmblk, int& bnblk){
  int gx = gridDim.x, gy = gridDim.y;
  int id = blockIdx.y * gx + blockIdx.x;
  int xcd = id & 7, local = id >> 3;
  bnblk = local % gx;
  bmblk = xcd * (gy >> 3) + local / gx;
}

// ---------------- fused weight transposes: W[K][N] -> Wt[N][K], bf16 -------
__device__ __forceinline__ void tc_body(const float* __restrict__ W,
                                        unsigned short* __restrict__ Wt,
                                        int K, int N, int n0, int k0)
{
  __shared__ unsigned short Ts[32][33];
  int r = threadIdx.x >> 3, c0 = (threadIdx.x & 7) * 4;
  float4 w4 = *(const float4*)(W + (size_t)(k0+r)*N + n0 + c0);
  Ts[r][c0+0] = f2bf(w4.x); Ts[r][c0+1] = f2bf(w4.y);
  Ts[r][c0+2] = f2bf(w4.z); Ts[r][c0+3] = f2bf(w4.w);
  __syncthreads();
  unsigned v0 = Ts[c0+0][r], v1 = Ts[c0+1][r], v2 = Ts[c0+2][r], v3 = Ts[c0+3][r];
  uint2 p; p.x = v0 | (v1<<16); p.y = v2 | (v3<<16);
  *(uint2*)(Wt + (size_t)(n0+r)*K + k0 + c0) = p;
}

__global__ __launch_bounds__(256)
void transpose_qkvo(const float* __restrict__ w0, unsigned short* __restrict__ t0,
                    const float* __restrict__ w1, unsigned short* __restrict__ t1,
                    const float* __restrict__ w2, unsigned short* __restrict__ t2,
                    const float* __restrict__ w3, unsigned short* __restrict__ t3)
{
  int z = blockIdx.z;
  const float* W = z==0 ? w0 : z==1 ? w1 : z==2 ? w2 : w3;
  unsigned short* T = z==0 ? t0 : z==1 ? t1 : z==2 ? t2 : t3;
  tc_body(W, T, Dz, Dz, blockIdx.x*32, blockIdx.y*32);
}

__global__ __launch_bounds__(256)
void transpose_ffn(const float* __restrict__ w1, unsigned short* __restrict__ w1T,
                   const float* __restrict__ w2, unsigned short* __restrict__ w2T)
{
  int z = blockIdx.z;
  const float* W = z ? w2 : w1;
  unsigned short* T = z ? w2T : w1T;
  int K = z ? Fz : Dz, N = z ? Dz : Fz;
  int n0 = (z ? blockIdx.y : blockIdx.x) * 32;
  int k0 = (z ? blockIdx.x : blockIdx.y) * 32;
  tc_body(W, T, K, N, n0, k0);
}

// ---------------- V transpose (bf16) + row-sum (for vmean) ------------------
__global__ __launch_bounds__(256)
void transpose_bf(const unsigned short* __restrict__ V, unsigned short* __restrict__ VT,
                  float* __restrict__ vsum)
{
  __shared__ unsigned short Ts[32][33];
  int st = blockIdx.x*32;           // s-tile
  int R0 = blockIdx.y*32;           // output-row tile (R = (b*16+h)*64+d)
  int b = R0 >> 10, hd0 = R0 & 1023;
  int r = threadIdx.x >> 3, c0 = (threadIdx.x & 7) * 4;
  uint2 w = *(const uint2*)(V + (size_t)(b*Sz + st + r)*Dz + hd0 + c0);
  Ts[r][c0+0] = (unsigned short)(w.x & 0xffff);
  Ts[r][c0+1] = (unsigned short)(w.x >> 16);
  Ts[r][c0+2] = (unsigned short)(w.y & 0xffff);
  Ts[r][c0+3] = (unsigned short)(w.y >> 16);
  __syncthreads();
  unsigned v0 = Ts[c0+0][r], v1 = Ts[c0+1][r], v2 = Ts[c0+2][r], v3 = Ts[c0+3][r];
  uint2 p; p.x = v0 | (v1<<16); p.y = v2 | (v3<<16);
  *(uint2*)(VT + (size_t)(R0+r)*Sz + st + c0) = p;
  float s = bf2f((unsigned short)v0) + bf2f((unsigned short)v1)
          + bf2f((unsigned short)v2) + bf2f((unsigned short)v3);
  s += __shfl_down(s, 1, 8);
  s += __shfl_down(s, 2, 8);
  s += __shfl_down(s, 4, 8);
  if ((threadIdx.x & 7) == 0) atomicAdd(vsum + R0 + r, s);
}

// ---------------- LayerNorm: fp32 in -> bf16 out, one block per row --------
__global__ __launch_bounds__(256)
void ln_kernel(const float* __restrict__ in, const float* __restrict__ gam,
               const float* __restrict__ bet, unsigned short* __restrict__ out)
{
  int row = blockIdx.x, t = threadIdx.x;
  size_t base = (size_t)row * Dz;
  int c0 = t * 4;
  float4 x4 = *(const float4*)(in + base + c0);
  float v[4] = {x4.x, x4.y, x4.z, x4.w};
  float s = v[0]+v[1]+v[2]+v[3];
  #pragma unroll
  for (int off=32; off>0; off>>=1) s += __shfl_down(s, off, 64);
  __shared__ float ws[4];
  int lane = t & 63, wid = t >> 6;
  if (lane == 0) ws[wid] = s;
  __syncthreads();
  float mu = (ws[0]+ws[1]+ws[2]+ws[3]) * (1.0f/Dz);
  __syncthreads();
  float d0=v[0]-mu, d1=v[1]-mu, d2=v[2]-mu, d3=v[3]-mu;
  float s2 = d0*d0+d1*d1+d2*d2+d3*d3;
  #pragma unroll
  for (int off=32; off>0; off>>=1) s2 += __shfl_down(s2, off, 64);
  if (lane == 0) ws[wid] = s2;
  __syncthreads();
  float var = (ws[0]+ws[1]+ws[2]+ws[3]) * (1.0f/Dz);
  float rstd = rsqrtf(var + EPSf);
  float4 g4 = *(const float4*)(gam + c0);
  float4 b4 = *(const float4*)(bet + c0);
  unsigned r0 = f2bf((v[0]-mu)*rstd*g4.x + b4.x);
  unsigned r1 = f2bf((v[1]-mu)*rstd*g4.y + b4.y);
  unsigned r2 = f2bf((v[2]-mu)*rstd*g4.z + b4.z);
  unsigned r3 = f2bf((v[3]-mu)*rstd*g4.w + b4.w);
  uint2 p; p.x = r0 | (r1<<16); p.y = r2 | (r3<<16);
  *(uint2*)(out + base + c0) = p;
}

// ===========================================================================
// 256x256-tile, BK=64, 8-wave GEMM — 4-phase/iter single-barrier schedule.
// Theory: per-barrier sync overhead dominates (all pipes <30%); halve the
// barrier count by doing 32 MFMA per phase (full j-range per A-half).
// Per phase: reads(p); STG(p); lgkmcnt(0); [vmcnt]; s_barrier; 32xMFMA.
// Pairing: P1 buf0 Lo x j0..3 (reads A-Lo 8 + B 8); P2 buf0 Hi x j0..3
// (reads A-Hi 8, b01/b23 held); P3/P4 same on buf1.
// Staging (4 gload16/phase; region last-read >=1 barrier before stage):
//   P1: buf1.A(2t+1)        [Ah0 last read P3(t-1), Ah1 P4(t-1)]
//   P2: buf0.{Ah0,Bjh0}(2t+2) [both last read P1] + vmcnt(4):
//       drains P4'(4)+P1(4) = buf1(2t+1) complete before P3 reads it
//   P3: buf0.{Ah1,Bjh1}(2t+2) [Ah1 last read P2, Bjh1 P1]
//   P4: buf1.B(2t+3)        [last read P3] + vmcnt(4):
//       drains P2(4)+P3(4) = buf0(2t+2) complete before next-iter P1
// Steady state: 4 issued/phase, 12 before each counted wait, drain to 4.
// Prologue: buf0 full (8) + buf1.B (4), vmcnt(4) proves buf0. Last iter:
// P2 uses vmcnt(0) (no new issues to push the count).
// ===========================================================================
#define STG_A(buf, half, k0) { \
  _Pragma("unroll") for (int c_=0;c_<2;c_++){ \
    int sg_ = c_*8 + wave; \
    int row0_ = ((sg_>>3)<<7) + ((sg_&7)<<3) + ((half)<<6); \
    gload16(pA[half][c_] + (k0), &As[buf][row0_*64]); } }

#define STG_B(buf, jh, k0) { \
  _Pragma("unroll") for (int c_=0;c_<2;c_++){ \
    int sg_ = c_*8 + wave; int rho0_ = sg_<<3; \
    gload16(pB[jh][c_] + (k0), &Bs[buf][jh][rho0_*64]); } }

#define READ_A4(dst, buf, ihalf) { \
  _Pragma("unroll") for (int ii_=0; ii_<4; ++ii_){ \
    int row_ = wm*128 + ((ihalf)*4+ii_)*16 + l15; \
    _Pragma("unroll") for (int ks_=0; ks_<2; ++ks_){ \
      int slot_ = (ks_*4+quad) ^ (l15&7); \
      dst[ii_][ks_] = *(const short8*)&As[buf][row_*64 + slot_*8]; } } }

#define READ_B2(dst, buf, jh) { \
  _Pragma("unroll") for (int jl_=0; jl_<2; ++jl_){ \
    int rho_ = wn*32 + jl_*16 + l15; \
    _Pragma("unroll") for (int ks_=0; ks_<2; ++ks_){ \
      int slot_ = (ks_*4+quad) ^ (l15&7); \
      dst[jl_][ks_] = *(const short8*)&Bs[buf][jh][rho_*64 + slot_*8]; } } }

#define MFMA_PH(IH, JH, AF, BF) { \
  __builtin_amdgcn_s_setprio(1); \
  _Pragma("unroll") for (int ii_=0; ii_<4; ++ii_){ \
    _Pragma("unroll") for (int jl_=0; jl_<2; ++jl_){ \
      floatx4 c_ = acc[(IH)*4+ii_][(JH)*2+jl_]; \
      c_ = __builtin_amdgcn_mfma_f32_16x16x32_bf16(AF[ii_][0], BF[jl_][0], c_, 0,0,0); \
      c_ = __builtin_amdgcn_mfma_f32_16x16x32_bf16(AF[ii_][1], BF[jl_][1], c_, 0,0,0); \
      acc[(IH)*4+ii_][(JH)*2+jl_] = c_; } } \
  __builtin_amdgcn_s_setprio(0); }

__global__ __launch_bounds__(512, 2)
void gemm256(const unsigned short* __restrict__ A,
             const unsigned short* __restrict__ Bt,
             const float* __restrict__ bias, const float* __restrict__ res,
             float* __restrict__ outf, unsigned short* __restrict__ outb,
             int M, int N, int K, int lda, int ldb, int act, int qkvmode)
{
  __shared__ unsigned short As[2][256*64];     // [buf][row(256)][k(64)], swizzled slots
  __shared__ unsigned short Bs[2][2][128*64];  // [buf][jh][wn*32+jl*16+l15][k(64)]

  int t = threadIdx.x;
  int wave = t >> 6, lane = t & 63;
  int l15 = lane & 15, quad = lane >> 4;
  int wm = wave >> 2, wn = wave & 3;           // 2x4 wave grid, wave tile 128x64

  int nN = gridDim.x, nM = gridDim.y;
  int id = blockIdx.y * nN + blockIdx.x;
  int xcd = id & 7, local = id >> 3;
  int bnblk = local % nN;
  int bmblk = xcd * (nM >> 3) + local / nN;
  int bm = bmblk * 256, bn = bnblk * 256;

  if (gridDim.z > 1){
    A    += (size_t)blockIdx.z * K;
    Bt   += (size_t)blockIdx.z * K;
    outf += (size_t)blockIdx.z * ((size_t)M * N);
  }

  int lrow = lane >> 3;                         // 0..7 rows within a 1KB piece
  int lcol = ((lane & 7) ^ (lane >> 3)) * 8;    // inverse-swizzled source chunk

  const unsigned short* pA[2][2];
  const unsigned short* pB[2][2];
  #pragma unroll
  for (int half=0; half<2; half++)
    #pragma unroll
    for (int c=0;c<2;c++){
      int sg = c*8 + wave;
      int row0 = ((sg>>3)<<7) + ((sg&7)<<3) + (half<<6);
      pA[half][c] = A + (size_t)(bm + row0 + lrow)*lda + lcol;
    }
  #pragma unroll
  for (int jh=0; jh<2; jh++)
    #pragma unroll
    for (int c=0;c<2;c++){
      int sg = c*8 + wave;
      int rho0 = sg<<3;
      int gn = ((rho0>>5)<<6) + (jh<<5) + (rho0&31);
      pB[jh][c] = Bt + (size_t)(bn + gn + lrow)*ldb + lcol;
    }

  floatx4 acc[8][4];
  #pragma unroll
  for (int i=0;i<8;i++)
    #pragma unroll
    for (int j=0;j<4;j++) acc[i][j] = (floatx4){0.f,0.f,0.f,0.f};

  // prologue: buf0 full (8 loads) + buf1.B (4 loads); buf1.A comes at P1(0)
  STG_A(0, 0, 0);  STG_A(0, 1, 0);
  STG_B(0, 0, 0);  STG_B(0, 1, 0);
  STG_B(1, 0, 64); STG_B(1, 1, 64);
  WAITV4;                      // drains buf0's 8; buf1.B's 4 in flight
  bar();

  int NKT = K >> 6;
  int nIter = NKT >> 1;
  for (int it = 0; it < nIter; ++it){
    bool more = (it + 1 < nIter);
    int k0B  = (2*it+1) << 6;
    int k0A2 = (2*it+2) << 6;
    int k0B2 = (2*it+3) << 6;
    short8 aLo[4][2], aHi[4][2], b01[2][2], b23[2][2];

    // ---- P1: buf0, Lo x j0..3 ----
    READ_A4(aLo, 0, 0);
    READ_B2(b01, 0, 0);
    READ_B2(b23, 0, 1);
    STG_A(1, 0, k0B); STG_A(1, 1, k0B);
    WL0; bar();
    MFMA_PH(0, 0, aLo, b01);
    MFMA_PH(0, 1, aLo, b23);

    // ---- P2: buf0, Hi x j0..3 (b held) ----
    READ_A4(aHi, 0, 1);
    if (more) { STG_A(0, 0, k0A2); STG_B(0, 0, k0A2); WAITV4; }
    else      { WAITV0; }
    WL0; bar();
    MFMA_PH(1, 0, aHi, b01);
    MFMA_PH(1, 1, aHi, b23);

    // ---- P3: buf1, Lo x j0..3 ----
    READ_A4(aLo, 1, 0);
    READ_B2(b01, 1, 0);
    READ_B2(b23, 1, 1);
    if (more) { STG_A(0, 1, k0A2); STG_B(0, 1, k0A2); }
    WL0; bar();
    MFMA_PH(0, 0, aLo, b01);
    MFMA_PH(0, 1, aLo, b23);

    // ---- P4: buf1, Hi x j0..3 ----
    READ_A4(aHi, 1, 1);
    if (more) { STG_B(1, 0, k0B2); STG_B(1, 1, k0B2); WAITV4; }
    WL0; bar();
    MFMA_PH(1, 0, aHi, b01);
    MFMA_PH(1, 1, aHi, b23);
  }

  float bj[4];
  #pragma unroll
  for (int j=0;j<4;j++) bj[j] = bias ? bias[bn + wn*64 + j*16 + l15] : 0.f;

  size_t selbase = 0; int ncol = N; int bnl = bn;
  if (qkvmode){ selbase = (size_t)(bn >> 10) * ((size_t)M * 1024); ncol = 1024; bnl = bn & 1023; }

  #pragma unroll
  for (int i=0;i<8;i++){
    int row0 = bm + wm*128 + i*16 + quad*4;
    #pragma unroll
    for (int r=0;r<4;r++){
      size_t rowoff = selbase + (size_t)(row0 + r) * ncol;
      #pragma unroll
      for (int j=0;j<4;j++){
        float v = acc[i][j][r] + bj[j];
        if (act) v = fast_gelu(v);
        size_t off = rowoff + bnl + wn*64 + j*16 + l15;
        if (res) v += res[off];
        if (outf) outf[off] = v;
        else      outb[off] = f2bf(v);
      }
    }
  }
}

// ---------------- MFMA GEMM 128x64, BK=64, double-buffered ------------------
__global__ __launch_bounds__(256)
void gemm_n64(const unsigned short* __restrict__ A,
              const unsigned short* __restrict__ Bt,
              const float* __restrict__ bias, const float* __restrict__ res,
              float* __restrict__ outf, unsigned short* __restrict__ outb,
              int M, int N, int K)
{
  __shared__ unsigned short As[2][128*64];   // [m][k], swizzled blocks
  __shared__ unsigned short Bs[2][64*64];    // [n][k]
  int t = threadIdx.x;
  int bmblk, bnblk; xcd_remap(bmblk, bnblk);
  int bm = bmblk * 128, bn = bnblk * 64;
  int wave = t >> 6, lane = t & 63;
  int l15 = lane & 15, quad = lane >> 4;
  int arow = lane >> 3;
  int acbg = ((lane & 7) ^ arow) * 8;
  const unsigned short* gA = A  + (size_t)(bm + wave*32 + arow)*K + acbg;
  const unsigned short* gB = Bt + (size_t)(bn + wave*16 + arow)*K + acbg;

  floatx4 acc[2][4];
  #pragma unroll
  for (int i=0;i<2;i++)
    #pragma unroll
    for (int j=0;j<4;j++) acc[i][j] = (floatx4){0.f,0.f,0.f,0.f};

  int swr = (l15 & 7);   // read-side XOR key

  { // prologue: tile 0 -> buffer 0
    unsigned short* lA = &As[0][wave*32*64];
    unsigned short* lB = &Bs[0][wave*16*64];
    gload16(gA,                 lA);
    gload16(gA + (size_t)8*K,   lA + 8*64);
    gload16(gA + (size_t)16*K,  lA + 16*64);
    gload16(gA + (size_t)24*K,  lA + 24*64);
    gload16(gB,                 lB);
    gload16(gB + (size_t)8*K,   lB + 8*64);
  }

  int nIter = K >> 6;
  for (int it = 0; it < nIter; ++it) {
    __syncthreads();
    int cur = it & 1;
    if (it + 1 < nIter) {
      int k1 = (it+1) << 6;
      unsigned short* lA = &As[cur^1][wave*32*64];
      unsigned short* lB = &Bs[cur^1][wave*16*64];
      gload16(gA + k1,                 lA);
      gload16(gA + k1 + (size_t)8*K,   lA + 8*64);
      gload16(gA + k1 + (size_t)16*K,  lA + 16*64);
      gload16(gA + k1 + (size_t)24*K,  lA + 24*64);
      gload16(gB + k1,                 lB);
      gload16(gB + k1 + (size_t)8*K,   lB + 8*64);
    }
    const unsigned short* Ac = As[cur];
    const unsigned short* Bc = Bs[cur];
    #pragma unroll
    for (int ks=0; ks<2; ++ks){
      short8 af[2], bf[4];
      #pragma unroll
      for (int i=0;i<2;i++)
        af[i] = *(const short8*)&Ac[(wave*32 + i*16 + l15)*64 + ((ks*4 + quad) ^ swr)*8];
      #pragma unroll
      for (int j=0;j<4;j++)
        bf[j] = *(const short8*)&Bc[(j*16 + l15)*64 + ((ks*4 + quad) ^ swr)*8];
      #pragma unroll
      for (int i=0;i<2;i++)
        #pragma unroll
        for (int j=0;j<4;j++)
          acc[i][j] = __builtin_amdgcn_mfma_f32_16x16x32_bf16(af[i], bf[j], acc[i][j], 0, 0, 0);
    }
  }

  float bj[4];
  #pragma unroll
  for (int j=0;j<4;j++) bj[j] = bias ? bias[bn + j*16 + l15] : 0.f;

  #pragma unroll
  for (int i=0;i<2;i++){
    int row0 = bm + wave*32 + i*16 + quad*4;
    #pragma unroll
    for (int r=0;r<4;r++){
      size_t rowoff = (size_t)(row0 + r) * N;
      #pragma unroll
      for (int j=0;j<4;j++){
        float v = acc[i][j][r] + bj[j];
        size_t off = rowoff + bn + j*16 + l15;
        if (res) v += res[off];
        if (outf) outf[off] = v;
        else      outb[off] = f2bf(v);
      }
    }
  }
}

// ---------------- split-K reduce: out = sum(part[0..3]) + bias + res --------
__global__ __launch_bounds__(256)
void reduce4(const float* __restrict__ part, const float* __restrict__ bias,
             const float* __restrict__ res, float* __restrict__ out)
{
  const size_t NN = (size_t)ROWS * Dz;
  size_t i = ((size_t)blockIdx.x * 256 + threadIdx.x) * 4;  // one block per row
  float4 a = *(const float4*)(part + i);
  float4 b = *(const float4*)(part + NN + i);
  float4 c = *(const float4*)(part + 2*NN + i);
  float4 d = *(const float4*)(part + 3*NN + i);
  float4 r = *(const float4*)(res + i);
  int col = threadIdx.x * 4;
  float4 g = *(const float4*)(bias + col);
  float4 o;
  o.x = a.x+b.x+c.x+d.x + g.x + r.x;
  o.y = a.y+b.y+c.y+d.y + g.y + r.y;
  o.z = a.z+b.z+c.z+d.z + g.z + r.z;
  o.w = a.w+b.w+c.w+d.w + g.w + r.w;
  *(float4*)(out + i) = o;
}

// ---------------- MFMA flash attention (verified) ---------------------------
#define ATT_STAGE_KV() { \
    *(uint4*)&Ks[sr*64 + ((kc2  ) ^ ksw)*8] = pk0; \
    *(uint4*)&Ks[sr*64 + ((kc2+1) ^ ksw)*8] = pk1; \
    *(uint4*)&Vts[vd*128 + (((vk8  )&8) | (((vk8  )^vsw)&7))*8] = pv0; \
    *(uint4*)&Vts[vd*128 + (((vk8+1)&8) | (((vk8+1)^vsw)&7))*8] = pv1; }

#define ATT_PREFETCH(tile) { \
    size_t off0_ = ((size_t)(b*Sz + (tile)*128 + sr))*Dz + h*HDz + sc; \
    pk0 = *(const uint4*)(Kg + off0_); pk1 = *(const uint4*)(Kg + off0_ + 8); \
    int vo_ = (tile)*128 + vc*16; \
    pv0 = *(const uint4*)(vrow + vo_); pv1 = *(const uint4*)(vrow + vo_ + 8); }

#define ATT_COMPUTE(MASKED) { \
  _Pragma("unroll") \
  for (int hh=0; hh<2; ++hh){ \
    floatx4 acc_s[4]; \
    _Pragma("unroll") for (int j=0;j<4;j++) acc_s[j] = (floatx4){0.f,0.f,0.f,0.f}; \
    __builtin_amdgcn_s_setprio(1); \
    _Pragma("unroll") \
    for (int ks=0;ks<2;ks++){ \
      short8 bk[4]; \
      _Pragma("unroll") \
      for (int j=0;j<4;j++) \
        bk[j] = *(const short8*)&Ks[(hh*64 + j*16 + l15)*64 + (((ks*4+quad) ^ (l15&7)))*8]; \
      _Pragma("unroll") \
      for (int j=0;j<4;j++) \
        acc_s[j] = __builtin_amdgcn_mfma_f32_16x16x32_bf16(aq[ks], bk[j], acc_s[j], 0, 0, 0); \
    } \
    __builtin_amdgcn_s_setprio(0); \
    _Pragma("unroll") \
    for (int j=0;j<4;j++){ \
      _Pragma("unroll") \
      for (int r=0;r<4;r++){ \
        float s2 = acc_s[j][r] * SC2f; \
        if (MASKED){ int kloc = hh*64 + j*16 + l15; if (kloc <= qloc + r) s2 = NEGf; } \
        float p = __builtin_amdgcn_exp2f(fminf(s2, 115.41f)); \
        lacc[r] += p; \
        Ps[wave*16 + quad*4 + r][j*16 + l15] = f2bf(p); \
      } \
    } \
    __builtin_amdgcn_s_setprio(1); \
    _Pragma("unroll") \
    for (int ks=0;ks<2;ks++){ \
      short8 ap, bv[4]; \
      ap = *(const short8*)&Ps[wave*16 + l15][ks*32 + quad*8]; \
      _Pragma("unroll") \
      for (int j=0;j<4;j++) \
        bv[j] = *(const short8*)&Vts[(j*16 + l15)*128 + (hh*8 + ((ks*4+quad) ^ (l15&7)))*8]; \
      _Pragma("unroll") \
      for (int j=0;j<4;j++) \
        acc_o[j] = __builtin_amdgcn_mfma_f32_16x16x32_bf16(ap, bv[j], acc_o[j], 0, 0, 0); \
    } \
    __builtin_amdgcn_s_setprio(0); \
  } }

__global__ __launch_bounds__(512, 4)
void attn_mfma(const unsigned short* __restrict__ Qg,
               const unsigned short* __restrict__ Kg,
               const unsigned short* __restrict__ VTg,
               const float* __restrict__ vmean,
               unsigned short* __restrict__ Og)
{
  __shared__ unsigned short Ks[128*64];    // [key][d], XOR-swizzled 8-chunks
  __shared__ unsigned short Vts[64*128];   // [d][key], XOR-swizzled 8-chunks
  __shared__ unsigned short Ps[128][72];   // Q staging, then P (wave-private 16-row stripes)

  int t = threadIdx.x;
  int wave = t >> 6, lane = t & 63;
  int l15 = lane & 15, quad = lane >> 4;
  int b = blockIdx.z, h = blockIdx.y;
  int qt = b ? (15 - (int)blockIdx.x) : (int)blockIdx.x;   // load-balance pairing

  { // stage Q tile (128 x 64) into Ps
    int r = t >> 2, c = (t & 3) * 16;
    const unsigned short* qp = Qg + ((size_t)(b*Sz + qt*128 + r))*Dz + h*HDz + c;
    uint4 q0 = *(const uint4*)(qp);
    uint4 q1 = *(const uint4*)(qp + 8);
    *(uint4*)&Ps[r][c]     = q0;
    *(uint4*)&Ps[r][c + 8] = q1;
  }

  int sr = t >> 2, sc = (t & 3) * 16;
  int kc2 = (t & 3) * 2, ksw = sr & 7;
  int vd = t >> 3, vc = t & 7, vsw = vd & 7;
  int vk8 = vc * 2;
  const unsigned short* vrow = VTg + ((size_t)((b*Hz + h)*64 + vd))*Sz;

  uint4 pk0, pk1, pv0, pv1;
  ATT_PREFETCH(qt);

  __syncthreads();
  short8 aq[2];
  aq[0] = *(const short8*)&Ps[wave*16 + l15][quad*8];
  aq[1] = *(const short8*)&Ps[wave*16 + l15][32 + quad*8];

  floatx4 acc_o[4];
  #pragma unroll
  for (int j=0;j<4;j++) acc_o[j] = (floatx4){0.f,0.f,0.f,0.f};
  float lacc[4] = {0.f, 0.f, 0.f, 0.f};

  int qloc = wave*16 + quad*4;   // q row within tile (plus r)

  // ---- diagonal tile (masked) ----
  ATT_STAGE_KV();
  __syncthreads();
  if (qt + 1 < Sz/128) ATT_PREFETCH(qt+1);
  ATT_COMPUTE(1);

  // ---- off-diagonal tiles (no mask: kj > qrow always) ----
  for (int jt2 = qt+1; jt2 < Sz/128; ++jt2){
    __syncthreads();
    ATT_STAGE_KV();
    __syncthreads();
    if (jt2 + 1 < Sz/128) ATT_PREFETCH(jt2+1);
    ATT_COMPUTE(0);
  }

  // ---- epilogue: reduce l across the 16 column-lanes, normalize, write ----
  #pragma unroll
  for (int r=0;r<4;r++){
    float l = lacc[r];
    l += __shfl_xor(l, 1, 64);
    l += __shfl_xor(l, 2, 64);
    l += __shfl_xor(l, 4, 64);
    l += __shfl_xor(l, 8, 64);
    int qrow = qt*128 + wave*16 + quad*4 + r;
    float inv = 1.0f / l;                 // row S-1: substituted below
    size_t rowoff = ((size_t)(b*Sz + qrow))*Dz + h*HDz;
    #pragma unroll
    for (int j=0;j<4;j++){
      float ov = acc_o[j][r] * inv;
      if (qrow == Sz-1) ov = vmean[(b*Hz + h)*HDz + j*16 + l15] * (1.0f/2048.0f);
      Og[rowoff + j*16 + l15] = f2bf(ov);
    }
  }
}

// ---------------------------------------------------------------------------
extern "C" void kernel_launch(void* const* d_in, const int* in_sizes, int n_in,
                              void* d_out, int out_size, void* d_ws, size_t ws_size,
                              hipStream_t stream)
{
  const float* x    = (const float*)d_in[0];
  const float* wq   = (const float*)d_in[1];
  const float* wk   = (const float*)d_in[2];
  const float* wv   = (const float*)d_in[3];
  const float* wo   = (const float*)d_in[4];
  const float* bo   = (const float*)d_in[5];
  const float* ln1g = (const float*)d_in[6];
  const float* ln1b = (const float*)d_in[7];
  const float* ln2g = (const float*)d_in[8];
  const float* ln2b = (const float*)d_in[9];
  const float* w1   = (const float*)d_in[10];
  const float* b1   = (const float*)d_in[11];
  const float* w2   = (const float*)d_in[12];
  const float* b2   = (const float*)d_in[13];
  float* out = (float*)d_out;

  const size_t MB = 1024*1024;
  char* w = (char*)d_ws;
  float*          trunk = (float*)(w);                  //  0..16  fp32 residual
  unsigned short* lnb   = (unsigned short*)(w + 16*MB); // 16..24  bf16 LN/a2
  unsigned short* q     = (unsigned short*)(w + 24*MB); // q,k,v contiguous 8 MB regions
  unsigned short* k     = (unsigned short*)(w + 32*MB);
  unsigned short* v     = (unsigned short*)(w + 40*MB);
  unsigned short* ctx   = (unsigned short*)(w + 48*MB);
  unsigned short* wqkvT = (unsigned short*)(w + 56*MB); // wq/wk/wv T concat [3072][1024]
  unsigned short* wqT   = wqkvT;
  unsigned short* wkT   = (unsigned short*)(w + 58*MB);
  unsigned short* wvT   = (unsigned short*)(w + 60*MB);
  unsigned short* woT   = (unsigned short*)(w + 62*MB);
  unsigned short* w1T   = (unsigned short*)(w + 64*MB); // [F][D] 8 MB
  unsigned short* w2T   = (unsigned short*)(w + 72*MB); // [D][F] 8 MB
  unsigned short* mid   = (unsigned short*)(w + 24*MB); // overlap: q/k/v/ctx dead
  float*          part  = (float*)(w + 80*MB);          // 64 MB split-K partials
  bool splitk = ws_size >= (size_t)144*MB;

  // d_out doubles as scratch before the final FFN2 write:
  //   vT (8 MB bf16 [2048][2048]) + vmean sums (8 KB fp32) — both dead by then.
  unsigned short* vT    = (unsigned short*)d_out;
  float*          vmean = (float*)((char*)d_out + 8*MB);

  dim3 blk(256), blk512(512);
  transpose_qkvo<<<dim3(32,32,4), blk, 0, stream>>>(wq, wqT, wk, wkT, wv, wvT, wo, woT);
  transpose_ffn<<<dim3(128,32,2), blk, 0, stream>>>(w1, w1T, w2, w2T);

  dim3 gln(ROWS);
  dim3 gqkv(3*Dz/256, ROWS/256);  // (12,16) fused QKV, 256^2 tiles
  dim3 gf1(Fz/256,  ROWS/256);    // (16,16) ffn1
  dim3 gn64(Dz/64,  ROWS/128);    // (16,32) = 512 blocks, 2/CU
  dim3 gattn(Sz/128, Hz, Bz);
  dim3 gvt(Sz/32, Bz*Hz*HDz/32);  // (64,64) V transpose

  // ---- block 1: h = attn(LN1(x)) + x ----
  ln_kernel<<<gln, blk, 0, stream>>>(x, ln1g, ln1b, lnb);
  gemm256<<<gqkv, blk512, 0, stream>>>(lnb, wqkvT, nullptr, nullptr, nullptr, q, ROWS, 3*Dz, Dz, Dz, Dz, 0, 1);
  hipMemsetAsync(vmean, 0, 2048*sizeof(float), stream);
  transpose_bf<<<gvt, blk, 0, stream>>>(v, vT, vmean);
  attn_mfma<<<gattn, blk512, 0, stream>>>(q, k, vT, vmean, ctx);
  gemm_n64<<<gn64, blk, 0, stream>>>(ctx, woT, bo, x, trunk, nullptr, ROWS, Dz, Dz);

  // ---- block 2: out = ffn(attn(LN2(h))) + h ----
  ln_kernel<<<gln, blk, 0, stream>>>(trunk, ln2g, ln2b, lnb);
  gemm256<<<gqkv, blk512, 0, stream>>>(lnb, wqkvT, nullptr, nullptr, nullptr, q, ROWS, 3*Dz, Dz, Dz, Dz, 0, 1);
  hipMemsetAsync(vmean, 0, 2048*sizeof(float), stream);
  transpose_bf<<<gvt, blk, 0, stream>>>(v, vT, vmean);
  attn_mfma<<<gattn, blk512, 0, stream>>>(q, k, vT, vmean, ctx);
  gemm_n64<<<gn64, blk, 0, stream>>>(ctx, woT, bo, nullptr, nullptr, lnb, ROWS, Dz, Dz);
  gemm256<<<gf1, blk512, 0, stream>>>(lnb, w1T, b1, nullptr, nullptr, mid, ROWS, Fz, Dz, Dz, Dz, 1, 0);
  if (splitk) {
    gemm256<<<dim3(4,16,4), blk512, 0, stream>>>(mid, w2T, nullptr, nullptr, part, nullptr, ROWS, Dz, Fz/4, Fz, Fz, 0, 0);
    reduce4<<<dim3(4096), blk, 0, stream>>>(part, b2, trunk, out);
  } else {
    gemm_n64<<<gn64, blk, 0, stream>>>(mid, w2T, b2, trunk, out, nullptr, ROWS, Dz, Fz);
  }
}